// Round 2
// baseline (1798.015 us; speedup 1.0000x reference)
//
#include <hip/hip_runtime.h>
#include <hip/hip_bf16.h>

// Problem constants
#define B  8
#define L  384
#define H  512
#define NH 8
#define DH 64
#define RR 769           // pe rows = 2*MAX_SEQ_LEN+1
#define SCALE 0.125f     // 1/sqrt(DH)

// out[r][c] = sum_k A[r][k] * W[c][k] + bias[c]   (all f32)
// cols = 512, K = 512. Block (16,16); each thread computes 4 cols spaced 16.
__global__ void gemm_nt_bias(const float* __restrict__ A,
                             const float* __restrict__ W,
                             const float* __restrict__ bias,
                             float* __restrict__ out, int rows) {
    __shared__ float As[16][17];
    __shared__ float Ws[64][17];
    const int tx = threadIdx.x, ty = threadIdx.y;
    const int r0 = blockIdx.y * 16;
    const int c0 = blockIdx.x * 64;
    float acc[4] = {0.f, 0.f, 0.f, 0.f};
    for (int k0 = 0; k0 < 512; k0 += 16) {
        int r = r0 + ty;
        As[ty][tx] = (r < rows) ? A[r * 512 + k0 + tx] : 0.f;
        #pragma unroll
        for (int i = 0; i < 4; i++) {
            int c = c0 + ty + i * 16;
            Ws[ty + i * 16][tx] = W[c * 512 + k0 + tx];
        }
        __syncthreads();
        #pragma unroll
        for (int t = 0; t < 16; t++) {
            float a = As[ty][t];
            acc[0] += a * Ws[tx][t];
            acc[1] += a * Ws[tx + 16][t];
            acc[2] += a * Ws[tx + 32][t];
            acc[3] += a * Ws[tx + 48][t];
        }
        __syncthreads();
    }
    int r = r0 + ty;
    if (r < rows) {
        #pragma unroll
        for (int i = 0; i < 4; i++) {
            int c = c0 + tx + i * 16;
            out[r * 512 + c] = acc[i] + bias[c];
        }
    }
}

// Dvec[h][m] = sum_d v_bias[h,d] * rproj[m, h*64+d]
__global__ void dvec_kernel(const float* __restrict__ rproj,
                            const float* __restrict__ v_bias,
                            float* __restrict__ Dvec) {
    int m = blockIdx.x, h = blockIdx.y, d = threadIdx.x;  // block = 64
    float val = v_bias[h * 64 + d] * rproj[m * 512 + h * 64 + d];
    #pragma unroll
    for (int off = 32; off > 0; off >>= 1) val += __shfl_down(val, off);
    if (d == 0) Dvec[h * RR + m] = val;
}

// Cb[b][h][j] = sum_d u_bias[h,d] * k[b,j,h,d]
__global__ void cbias_kernel(const float* __restrict__ k,
                             const float* __restrict__ u_bias,
                             float* __restrict__ Cb) {
    int j = blockIdx.x, h = blockIdx.y, b = blockIdx.z, d = threadIdx.x;  // block = 64
    float val = u_bias[h * 64 + d] * k[((b * L + j) * NH + h) * DH + d];
    #pragma unroll
    for (int off = 32; off > 0; off >>= 1) val += __shfl_down(val, off);
    if (d == 0) Cb[(b * NH + h) * L + j] = val;
}

// One block per (i, h, b): full score row, softmax, weighted sum of v.
__global__ void attn_kernel(const float* __restrict__ q, const float* __restrict__ k,
                            const float* __restrict__ v, const float* __restrict__ rproj,
                            const float* __restrict__ Dvec, const float* __restrict__ Cb,
                            const int* __restrict__ seq_len, float* __restrict__ O) {
    const int i = blockIdx.x, h = blockIdx.y, b = blockIdx.z;
    const int tid = threadIdx.x;  // 256
    __shared__ float qs[DH];
    __shared__ float sc[L];
    __shared__ float red[256];
    const int sl = seq_len[b];

    if (tid < DH) qs[tid] = q[((b * L + i) * NH + h) * DH + tid];
    __syncthreads();

    for (int j = tid; j < L; j += 256) {
        float s;
        if (j < sl) {
            const float* krow = &k[((b * L + j) * NH + h) * DH];
            const float* rrow = &rproj[(j - i + 384) * H + h * DH];
            float a = 0.f, bt = 0.f;
            #pragma unroll
            for (int d = 0; d < DH; d++) { a += qs[d] * krow[d]; bt += qs[d] * rrow[d]; }
            s = (a + bt + Cb[(b * NH + h) * L + j] + Dvec[h * RR + (j - i + 384)]) * SCALE;
        } else {
            s = -1e30f;
        }
        sc[j] = s;
    }
    __syncthreads();

    // max reduce
    float m = sc[tid];
    if (tid + 256 < L) m = fmaxf(m, sc[tid + 256]);
    red[tid] = m;
    __syncthreads();
    for (int s2 = 128; s2 > 0; s2 >>= 1) {
        if (tid < s2) red[tid] = fmaxf(red[tid], red[tid + s2]);
        __syncthreads();
    }
    const float mx = red[0];
    __syncthreads();

    // exp + sum
    float lsum = 0.f;
    for (int j = tid; j < L; j += 256) {
        float e = __expf(sc[j] - mx);
        sc[j] = e;
        lsum += e;
    }
    red[tid] = lsum;
    __syncthreads();
    for (int s2 = 128; s2 > 0; s2 >>= 1) {
        if (tid < s2) red[tid] += red[tid + s2];
        __syncthreads();
    }
    const float inv = 1.f / red[0];
    __syncthreads();

    // out[d] = inv * sum_j sc[j] * v[b,j,h,d]
    const int d = tid & 63, ch = tid >> 6;
    float acc = 0.f;
    for (int j = ch; j < L; j += 4) acc += sc[j] * v[((b * L + j) * NH + h) * DH + d];
    red[tid] = acc;
    __syncthreads();
    if (tid < 64) {
        float o = (red[tid] + red[tid + 64] + red[tid + 128] + red[tid + 192]) * inv;
        O[((b * L + i) * NH + h) * DH + tid] = o;
    }
}

// out[r][c] = sum_k A[r][k] * Wff[c][k] + bff[c]   (all f32)
__global__ void gemm_ff(const float* __restrict__ A,
                        const float* __restrict__ W,
                        const float* __restrict__ bias,
                        float* __restrict__ out) {
    __shared__ float As[16][17];
    __shared__ float Ws[64][17];
    const int tx = threadIdx.x, ty = threadIdx.y;
    const int r0 = blockIdx.y * 16;
    const int c0 = blockIdx.x * 64;
    float acc[4] = {0.f, 0.f, 0.f, 0.f};
    for (int k0 = 0; k0 < 512; k0 += 16) {
        As[ty][tx] = A[(r0 + ty) * 512 + k0 + tx];
        #pragma unroll
        for (int i = 0; i < 4; i++) {
            int c = c0 + ty + i * 16;
            Ws[ty + i * 16][tx] = W[c * 512 + k0 + tx];
        }
        __syncthreads();
        #pragma unroll
        for (int t = 0; t < 16; t++) {
            float a = As[ty][t];
            acc[0] += a * Ws[tx][t];
            acc[1] += a * Ws[tx + 16][t];
            acc[2] += a * Ws[tx + 32][t];
            acc[3] += a * Ws[tx + 48][t];
        }
        __syncthreads();
    }
    int r = r0 + ty;
    #pragma unroll
    for (int i = 0; i < 4; i++) {
        int c = c0 + tx + i * 16;
        out[r * 512 + c] = acc[i] + bias[c];
    }
}

extern "C" void kernel_launch(void* const* d_in, const int* in_sizes, int n_in,
                              void* d_out, int out_size, void* d_ws, size_t ws_size,
                              hipStream_t stream) {
    const float* key    = (const float*)d_in[0];
    const float* query  = (const float*)d_in[1];
    const float* value  = (const float*)d_in[2];
    const int*   seqlen = (const int*)d_in[3];
    const float* pe     = (const float*)d_in[4];
    const float* Wk     = (const float*)d_in[5];
    const float* bk     = (const float*)d_in[6];
    const float* Wq     = (const float*)d_in[7];
    const float* bq     = (const float*)d_in[8];
    const float* Wv     = (const float*)d_in[9];
    const float* bv     = (const float*)d_in[10];
    const float* Wr     = (const float*)d_in[11];
    const float* br     = (const float*)d_in[12];
    const float* u_bias = (const float*)d_in[13];
    const float* v_bias = (const float*)d_in[14];
    const float* Wff    = (const float*)d_in[15];
    const float* bff    = (const float*)d_in[16];

    const int NTOK = B * L;              // 3072
    float* ws    = (float*)d_ws;
    float* q     = ws;                    // 3072*512
    float* k     = q + NTOK * H;
    float* v     = k + NTOK * H;
    float* O     = v + NTOK * H;
    float* rproj = O + NTOK * H;          // 769*512
    float* Dvec  = rproj + RR * H;        // 8*769
    float* Cb    = Dvec + NH * RR;        // 8*8*384

    dim3 blk(16, 16);
    gemm_nt_bias<<<dim3(8, NTOK / 16), blk, 0, stream>>>(query, Wq, bq, q, NTOK);
    gemm_nt_bias<<<dim3(8, NTOK / 16), blk, 0, stream>>>(key,   Wk, bk, k, NTOK);
    gemm_nt_bias<<<dim3(8, NTOK / 16), blk, 0, stream>>>(value, Wv, bv, v, NTOK);
    gemm_nt_bias<<<dim3(8, (RR + 15) / 16), blk, 0, stream>>>(pe, Wr, br, rproj, RR);

    dvec_kernel<<<dim3(RR, NH), 64, 0, stream>>>(rproj, v_bias, Dvec);
    cbias_kernel<<<dim3(L, NH, B), 64, 0, stream>>>(k, u_bias, Cb);

    attn_kernel<<<dim3(L, NH, B), 256, 0, stream>>>(q, k, v, rproj, Dvec, Cb, seqlen, O);

    gemm_ff<<<dim3(8, NTOK / 16), blk, 0, stream>>>(O, Wff, bff, (float*)d_out);
}

// Round 3
// 459.113 us; speedup vs baseline: 3.9163x; 3.9163x over previous
//
#include <hip/hip_runtime.h>
#include <hip/hip_bf16.h>

// Problem constants
#define B_  8
#define L_  384
#define H_  512
#define NH_ 8
#define DH_ 64
#define NTOK 3072          // B*L
#define RRM 768            // rproj rows computed (band uses [1,767])

typedef short bf16x8 __attribute__((ext_vector_type(8)));
typedef float f32x4  __attribute__((ext_vector_type(4)));
#define MFMA_BF16 __builtin_amdgcn_mfma_f32_16x16x32_bf16

static __device__ __forceinline__ short f2bf(float f) {
    unsigned u = __builtin_bit_cast(unsigned, f);
    u += 0x7fffu + ((u >> 16) & 1u);           // RNE
    return (short)(u >> 16);
}
static __device__ __forceinline__ float bf2f(unsigned short s) {
    unsigned u = ((unsigned)s) << 16;
    return __builtin_bit_cast(float, u);
}
static __device__ __forceinline__ bf16x8 load_cvt8(const float* __restrict__ p) {
    bf16x8 r;
    #pragma unroll
    for (int t = 0; t < 8; t++) r[t] = f2bf(p[t]);
    return r;
}
static __device__ __forceinline__ bf16x8 ldfrag(const unsigned short* p) {
    return *(const bf16x8*)p;
}

// ---------------------------------------------------------------------------
// Generic MFMA GEMM: C[r][c] = sum_k A[r][k]*W[c][k] + bias[c], K=512.
// Block 256 = 4 waves; tile M=64 (wave=16 rows), N=128 (8 n-subs).
// A fp32 row-major [rows x 512]; W fp32 [512 x 512]; outputs per MODE.
// ---------------------------------------------------------------------------
enum { M_QUQV = 0, M_K = 1, M_VT = 2, M_RP = 3, M_FF = 4 };

template <int MODE>
__launch_bounds__(256)
__global__ void gemm512(const float* __restrict__ A, const float* __restrict__ W,
                        const float* __restrict__ bias, const float* __restrict__ biasU,
                        const float* __restrict__ biasV,
                        void* __restrict__ out0v, void* __restrict__ out1v) {
    const int lane = threadIdx.x & 63, wv = threadIdx.x >> 6;
    const int quad = lane >> 4, lm = lane & 15;
    const int r_fr = blockIdx.y * 64 + wv * 16 + lm;   // A row this lane loads
    const int n0 = blockIdx.x * 128;
    f32x4 acc[8] = {};
    const float* arow = A + (long)r_fr * 512 + quad * 8;
    for (int kc = 0; kc < 16; kc++) {
        bf16x8 af = load_cvt8(arow + kc * 32);
        #pragma unroll
        for (int ns = 0; ns < 8; ns++) {
            const float* wrow = W + (long)(n0 + ns * 16 + lm) * 512 + kc * 32 + quad * 8;
            acc[ns] = MFMA_BF16(af, load_cvt8(wrow), acc[ns], 0, 0, 0);
        }
    }
    #pragma unroll
    for (int ns = 0; ns < 8; ns++) {
        const int c = n0 + ns * 16 + lm;
        const int h = c >> 6, d = c & 63;
        #pragma unroll
        for (int reg = 0; reg < 4; reg++) {
            const int r = blockIdx.y * 64 + wv * 16 + quad * 4 + reg;
            const float val = acc[ns][reg] + bias[c];
            if (MODE == M_QUQV) {
                const int bb = r / L_, ii = r - bb * L_;
                const long idx = ((long)(bb * NH_ + h) * L_ + ii) * DH_ + d;
                ((unsigned short*)out0v)[idx] = (unsigned short)f2bf(val + biasU[c]);
                ((unsigned short*)out1v)[idx] = (unsigned short)f2bf(val + biasV[c]);
            } else if (MODE == M_K) {
                const int bb = r / L_, ii = r - bb * L_;
                ((unsigned short*)out0v)[((long)(bb * NH_ + h) * L_ + ii) * DH_ + d] =
                    (unsigned short)f2bf(val);
            } else if (MODE == M_VT) {
                const int bb = r / L_, ii = r - bb * L_;
                ((unsigned short*)out0v)[((long)(bb * NH_ + h) * DH_ + d) * L_ + ii] =
                    (unsigned short)f2bf(val);
            } else if (MODE == M_RP) {
                ((unsigned short*)out0v)[(long)r * 512 + c] = (unsigned short)f2bf(val);
            } else {  // M_FF
                ((float*)out0v)[(long)r * 512 + c] = val;
            }
        }
    }
}

// ---------------------------------------------------------------------------
// Btfull[bh][i][m] = sum_d qv[bh][i][d] * rproj[m][h*64+d],  M=384, N=768, K=64
// Block 256: i-tile 64 (wave=16 rows), m-tile 128.
// ---------------------------------------------------------------------------
__launch_bounds__(256)
__global__ void btfull_kernel(const unsigned short* __restrict__ qv,
                              const unsigned short* __restrict__ rproj,
                              unsigned short* __restrict__ Bt) {
    const int lane = threadIdx.x & 63, wv = threadIdx.x >> 6;
    const int quad = lane >> 4, lm = lane & 15;
    const int bh = blockIdx.z, h = bh & (NH_ - 1);
    const int i0 = blockIdx.y * 64, m0 = blockIdx.x * 128;
    const int i_fr = i0 + wv * 16 + lm;
    const unsigned short* qrow = qv + ((long)bh * L_ + i_fr) * DH_;
    const bf16x8 a0 = ldfrag(qrow + quad * 8);
    const bf16x8 a1 = ldfrag(qrow + 32 + quad * 8);
    f32x4 acc[8] = {};
    #pragma unroll
    for (int ns = 0; ns < 8; ns++) {
        const unsigned short* rrow = rproj + (long)(m0 + ns * 16 + lm) * 512 + h * 64 + quad * 8;
        acc[ns] = MFMA_BF16(a0, ldfrag(rrow), acc[ns], 0, 0, 0);
        acc[ns] = MFMA_BF16(a1, ldfrag(rrow + 32), acc[ns], 0, 0, 0);
    }
    #pragma unroll
    for (int ns = 0; ns < 8; ns++) {
        const int m = m0 + ns * 16 + lm;
        #pragma unroll
        for (int reg = 0; reg < 4; reg++) {
            const int i = i0 + wv * 16 + quad * 4 + reg;
            Bt[((long)bh * L_ + i) * RRM + m] = (unsigned short)f2bf(acc[ns][reg]);
        }
    }
}

// ---------------------------------------------------------------------------
// Fused attention: per (bh, 32-row i-tile):
//   S = (qu·k^T + band(Bt)) * 0.125, masked  -> LDS
//   row softmax -> P bf16 in LDS
//   O = P @ v  (MFMA vs vT)                  -> token-major fp32
// ---------------------------------------------------------------------------
#define SSTR 401
#define PSTR 392
__launch_bounds__(256)
__global__ void attn_fused(const unsigned short* __restrict__ qu,
                           const unsigned short* __restrict__ kbf,
                           const unsigned short* __restrict__ vT,
                           const unsigned short* __restrict__ Bt,
                           const int* __restrict__ seq_len,
                           float* __restrict__ O) {
    __shared__ float S[32 * SSTR];
    __shared__ unsigned short P[32 * PSTR];
    const int lane = threadIdx.x & 63, wv = threadIdx.x >> 6;
    const int quad = lane >> 4, lm = lane & 15;
    const int bh = blockIdx.y, b = bh >> 3, h = bh & 7;
    const int i0 = blockIdx.x * 32;
    const int sl = seq_len[b];

    // ---- phase 1: score tile via MFMA ----
    const int msub = wv & 1, nh = wv >> 1;   // wave covers 16 rows x 192 cols
    {
        const int i_fr = i0 + msub * 16 + lm;
        const unsigned short* qrow = qu + ((long)bh * L_ + i_fr) * DH_;
        const bf16x8 a0 = ldfrag(qrow + quad * 8);
        const bf16x8 a1 = ldfrag(qrow + 32 + quad * 8);
        f32x4 acc[12] = {};
        #pragma unroll
        for (int ns = 0; ns < 12; ns++) {
            const int j = nh * 192 + ns * 16 + lm;
            const unsigned short* krow = kbf + ((long)bh * L_ + j) * DH_;
            acc[ns] = MFMA_BF16(a0, ldfrag(krow + quad * 8), acc[ns], 0, 0, 0);
            acc[ns] = MFMA_BF16(a1, ldfrag(krow + 32 + quad * 8), acc[ns], 0, 0, 0);
        }
        #pragma unroll
        for (int ns = 0; ns < 12; ns++) {
            #pragma unroll
            for (int reg = 0; reg < 4; reg++) {
                const int il = msub * 16 + quad * 4 + reg;
                const int i = i0 + il;
                const int j = nh * 192 + ns * 16 + lm;
                float val = -1e30f;
                if (j < sl) {
                    const float bt = bf2f(Bt[((long)bh * L_ + i) * RRM + (j - i + 384)]);
                    val = (acc[ns][reg] + bt) * 0.125f;
                }
                S[il * SSTR + j] = val;
            }
        }
    }
    __syncthreads();

    // ---- phase 2: row softmax (8 threads per row) ----
    {
        const int row = threadIdx.x >> 3, sub = threadIdx.x & 7;
        float mx = -1e30f;
        for (int t = sub; t < L_; t += 8) mx = fmaxf(mx, S[row * SSTR + t]);
        #pragma unroll
        for (int o = 1; o < 8; o <<= 1) mx = fmaxf(mx, __shfl_xor(mx, o, 8));
        float sum = 0.f;
        for (int t = sub; t < L_; t += 8) {
            const float e = __expf(S[row * SSTR + t] - mx);
            S[row * SSTR + t] = e;
            sum += e;
        }
        #pragma unroll
        for (int o = 1; o < 8; o <<= 1) sum += __shfl_xor(sum, o, 8);
        const float inv = 1.f / sum;
        for (int t = sub; t < L_; t += 8)
            P[row * PSTR + t] = (unsigned short)f2bf(S[row * SSTR + t] * inv);
    }
    __syncthreads();

    // ---- phase 3: O = P @ v via MFMA (wave: 16 rows x 32 d) ----
    {
        const int pr = msub * 16 + lm;
        f32x4 oacc[2] = {};
        #pragma unroll
        for (int kc = 0; kc < 12; kc++) {
            const bf16x8 af = ldfrag(P + pr * PSTR + kc * 32 + quad * 8);
            #pragma unroll
            for (int t = 0; t < 2; t++) {
                const int n = nh * 32 + t * 16 + lm;
                const unsigned short* vrow = vT + ((long)bh * DH_ + n) * L_ + kc * 32 + quad * 8;
                oacc[t] = MFMA_BF16(af, ldfrag(vrow), oacc[t], 0, 0, 0);
            }
        }
        #pragma unroll
        for (int t = 0; t < 2; t++) {
            #pragma unroll
            for (int reg = 0; reg < 4; reg++) {
                const int i = i0 + msub * 16 + quad * 4 + reg;
                const int d = nh * 32 + t * 16 + lm;
                O[((long)b * L_ + i) * H_ + h * DH_ + d] = oacc[t][reg];
            }
        }
    }
}

extern "C" void kernel_launch(void* const* d_in, const int* in_sizes, int n_in,
                              void* d_out, int out_size, void* d_ws, size_t ws_size,
                              hipStream_t stream) {
    const float* key    = (const float*)d_in[0];
    const float* query  = (const float*)d_in[1];
    const float* value  = (const float*)d_in[2];
    const int*   seqlen = (const int*)d_in[3];
    const float* pe     = (const float*)d_in[4];
    const float* Wk     = (const float*)d_in[5];
    const float* bk     = (const float*)d_in[6];
    const float* Wq     = (const float*)d_in[7];
    const float* bq     = (const float*)d_in[8];
    const float* Wv     = (const float*)d_in[9];
    const float* bv     = (const float*)d_in[10];
    const float* Wr     = (const float*)d_in[11];
    const float* br     = (const float*)d_in[12];
    const float* u_bias = (const float*)d_in[13];
    const float* v_bias = (const float*)d_in[14];
    const float* Wff    = (const float*)d_in[15];
    const float* bff    = (const float*)d_in[16];

    // workspace carve (bf16 stored as ushort)
    const size_t nHead = (size_t)B_ * NH_ * L_ * DH_;   // 1,572,864
    unsigned short* qu = (unsigned short*)d_ws;
    unsigned short* qv = qu + nHead;
    unsigned short* kb = qv + nHead;
    unsigned short* vT = kb + nHead;
    unsigned short* rp = vT + nHead;                    // 768*512
    unsigned short* Bt = rp + (size_t)RRM * 512;
    float* O = (float*)(Bt + (size_t)B_ * NH_ * L_ * RRM);

    // projections (fold u_bias / v_bias into q)
    gemm512<M_QUQV><<<dim3(4, 48), 256, 0, stream>>>(query, Wq, bq, u_bias, v_bias, qu, qv);
    gemm512<M_K>   <<<dim3(4, 48), 256, 0, stream>>>(key,   Wk, bk, nullptr, nullptr, kb, nullptr);
    gemm512<M_VT>  <<<dim3(4, 48), 256, 0, stream>>>(value, Wv, bv, nullptr, nullptr, vT, nullptr);
    gemm512<M_RP>  <<<dim3(4, 12), 256, 0, stream>>>(pe,    Wr, br, nullptr, nullptr, rp, nullptr);

    // content-position table
    btfull_kernel<<<dim3(RRM / 128, L_ / 64, B_ * NH_), 256, 0, stream>>>(qv, rp, Bt);

    // fused scores + softmax + PV
    attn_fused<<<dim3(L_ / 32, B_ * NH_), 256, 0, stream>>>(qu, kb, vT, Bt, seqlen, O);

    // output projection
    gemm512<M_FF><<<dim3(4, 48), 256, 0, stream>>>(O, Wff, bff, nullptr, nullptr, d_out, nullptr);
}

// Round 4
// 228.969 us; speedup vs baseline: 7.8526x; 2.0051x over previous
//
#include <hip/hip_runtime.h>
#include <hip/hip_bf16.h>

#define B_  8
#define L_  384
#define H_  512
#define NH_ 8
#define DH_ 64
#define RRM 768            // rproj rows computed; band uses [1,767]

typedef short bf16x8 __attribute__((ext_vector_type(8)));
typedef float f32x4  __attribute__((ext_vector_type(4)));
#define MFMA_BF16 __builtin_amdgcn_mfma_f32_16x16x32_bf16

static __device__ __forceinline__ unsigned short f2bf(float f) {
    unsigned u = __builtin_bit_cast(unsigned, f);
    u += 0x7fffu + ((u >> 16) & 1u);           // RNE
    return (unsigned short)(u >> 16);
}
static __device__ __forceinline__ float bf2f(unsigned short s) {
    unsigned u = ((unsigned)s) << 16;
    return __builtin_bit_cast(float, u);
}

// ---------------------------------------------------------------------------
// fp32 -> bf16 bulk convert. chunk = 1024 elems (256 thr x 4); regions listed
// in CvtArgs; every region size is a multiple of 1024 (no tails).
// ---------------------------------------------------------------------------
struct CvtArgs {
    const float* src[9];
    unsigned short* dst[9];
    int nchunks[9];
};
__global__ __launch_bounds__(256) void cvt_kernel(CvtArgs a) {
    int chunk = blockIdx.x;
    int r = 0;
    while (r < 8 && chunk >= a.nchunks[r]) { chunk -= a.nchunks[r]; r++; }
    const float4 v = ((const float4*)a.src[r])[chunk * 256 + threadIdx.x];
    ushort4 o;
    o.x = f2bf(v.x); o.y = f2bf(v.y); o.z = f2bf(v.z); o.w = f2bf(v.w);
    ((ushort4*)a.dst[r])[chunk * 256 + threadIdx.x] = o;
}

// ---------------------------------------------------------------------------
// bf16 NT GEMM, K=512, tile 64x64, BK=64, double-buffered LDS, 4 waves (2x2).
// IS_FF=false: grid (8, 48, 4); z selects {q,k,v,pe} with per-mode epilogues.
// IS_FF=true : grid (8, 48, 1); A=Obf, out fp32 d_out.
// ---------------------------------------------------------------------------
#define LDT 72   // padded LDS row stride (ushorts): 144 B -> <=2-way conflicts

template <bool IS_FF>
__global__ __launch_bounds__(256) void gemm_nt(
    const unsigned short* __restrict__ A0, const unsigned short* __restrict__ A1,
    const unsigned short* __restrict__ A2, const unsigned short* __restrict__ A3,
    const unsigned short* __restrict__ W0, const unsigned short* __restrict__ W1,
    const unsigned short* __restrict__ W2, const unsigned short* __restrict__ W3,
    const float* __restrict__ b0, const float* __restrict__ b1,
    const float* __restrict__ b2, const float* __restrict__ b3,
    const float* __restrict__ ub, const float* __restrict__ vbias,
    unsigned short* __restrict__ qu, unsigned short* __restrict__ qv,
    unsigned short* __restrict__ kb, unsigned short* __restrict__ vT,
    unsigned short* __restrict__ rp, float* __restrict__ ff) {

    const int z = IS_FF ? 4 : blockIdx.z;
    if (!IS_FF && z == 3 && blockIdx.y >= 12) return;   // pe has 768 rows
    const unsigned short* A = IS_FF ? A0 : (z == 0 ? A0 : z == 1 ? A1 : z == 2 ? A2 : A3);
    const unsigned short* W = IS_FF ? W0 : (z == 0 ? W0 : z == 1 ? W1 : z == 2 ? W2 : W3);
    const float* bias       = IS_FF ? b0 : (z == 0 ? b0 : z == 1 ? b1 : z == 2 ? b2 : b3);

    __shared__ unsigned short As[2][64 * LDT];
    __shared__ unsigned short Bs[2][64 * LDT];

    const int tid = threadIdx.x;
    const int w = tid >> 6, lane = tid & 63;
    const int quad = lane >> 4, lm = lane & 15;
    const int l8r = lane >> 3, l8c = lane & 7;
    const int wr = (w & 1) * 32, wc = (w >> 1) * 32;

    const unsigned short* ag = A + (size_t)(blockIdx.y * 64 + w * 16 + l8r) * 512 + l8c * 8;
    const unsigned short* wg = W + (size_t)(blockIdx.x * 64 + w * 16 + l8r) * 512 + l8c * 8;
    const int soff = (w * 16 + l8r) * LDT + l8c * 8;

    // prologue: stage chunk 0
    bf16x8 pa0 = *(const bf16x8*)(ag);
    bf16x8 pa1 = *(const bf16x8*)(ag + 8 * 512);
    bf16x8 pb0 = *(const bf16x8*)(wg);
    bf16x8 pb1 = *(const bf16x8*)(wg + 8 * 512);
    *(bf16x8*)&As[0][soff]            = pa0;
    *(bf16x8*)&As[0][soff + 8 * LDT]  = pa1;
    *(bf16x8*)&Bs[0][soff]            = pb0;
    *(bf16x8*)&Bs[0][soff + 8 * LDT]  = pb1;

    f32x4 acc[2][2] = {};
    for (int kc = 0; kc < 8; ++kc) {
        __syncthreads();
        const int buf = kc & 1;
        if (kc < 7) {                         // prefetch next chunk into regs
            const int k0 = (kc + 1) * 64;
            pa0 = *(const bf16x8*)(ag + k0);
            pa1 = *(const bf16x8*)(ag + k0 + 8 * 512);
            pb0 = *(const bf16x8*)(wg + k0);
            pb1 = *(const bf16x8*)(wg + k0 + 8 * 512);
        }
        #pragma unroll
        for (int ks = 0; ks < 2; ++ks) {
            bf16x8 a0 = *(const bf16x8*)&As[buf][(wr + lm) * LDT + ks * 32 + quad * 8];
            bf16x8 a1 = *(const bf16x8*)&As[buf][(wr + 16 + lm) * LDT + ks * 32 + quad * 8];
            bf16x8 w0 = *(const bf16x8*)&Bs[buf][(wc + lm) * LDT + ks * 32 + quad * 8];
            bf16x8 w1 = *(const bf16x8*)&Bs[buf][(wc + 16 + lm) * LDT + ks * 32 + quad * 8];
            acc[0][0] = MFMA_BF16(a0, w0, acc[0][0], 0, 0, 0);
            acc[0][1] = MFMA_BF16(a0, w1, acc[0][1], 0, 0, 0);
            acc[1][0] = MFMA_BF16(a1, w0, acc[1][0], 0, 0, 0);
            acc[1][1] = MFMA_BF16(a1, w1, acc[1][1], 0, 0, 0);
        }
        if (kc < 7) {                         // store prefetch into other buffer
            const int nb = buf ^ 1;
            *(bf16x8*)&As[nb][soff]           = pa0;
            *(bf16x8*)&As[nb][soff + 8 * LDT] = pa1;
            *(bf16x8*)&Bs[nb][soff]           = pb0;
            *(bf16x8*)&Bs[nb][soff + 8 * LDT] = pb1;
        }
    }

    #pragma unroll
    for (int si = 0; si < 2; ++si) {
        #pragma unroll
        for (int sj = 0; sj < 2; ++sj) {
            #pragma unroll
            for (int reg = 0; reg < 4; ++reg) {
                const int r = blockIdx.y * 64 + wr + si * 16 + quad * 4 + reg;
                const int c = blockIdx.x * 64 + wc + sj * 16 + lm;
                const float val = acc[si][sj][reg] + bias[c];
                if (IS_FF) {
                    ff[r * 512 + c] = val;
                } else if (z == 0) {
                    const int bb = r / L_, ii = r - bb * L_;
                    const int h = c >> 6, d = c & 63;
                    const int idx = ((bb * NH_ + h) * L_ + ii) * DH_ + d;
                    qu[idx] = f2bf((val + ub[c]) * 0.125f);     // pow2 scale: exact
                    qv[idx] = f2bf((val + vbias[c]) * 0.125f);
                } else if (z == 1) {
                    const int bb = r / L_, ii = r - bb * L_;
                    const int h = c >> 6, d = c & 63;
                    kb[((bb * NH_ + h) * L_ + ii) * DH_ + d] = f2bf(val);
                } else if (z == 2) {
                    const int bb = r / L_, ii = r - bb * L_;
                    const int h = c >> 6, d = c & 63;
                    vT[((bb * NH_ + h) * DH_ + d) * L_ + ii] = f2bf(val);
                } else {
                    rp[r * 512 + c] = f2bf(val);
                }
            }
        }
    }
}

// ---------------------------------------------------------------------------
// Btb[bh][i][j] = qv[bh][i] . rp[j-i+384][h*64..]: QR tile via MFMA from an
// LDS-staged rp tile, then band-shift through LDS, coalesced row writes.
// grid (6 m-tiles(128), 6 i-tiles(64), 64 bh), block 256.
// ---------------------------------------------------------------------------
__global__ __launch_bounds__(256) void btshift_kernel(
    const unsigned short* __restrict__ qv, const unsigned short* __restrict__ rp,
    unsigned short* __restrict__ Btb) {
    const int bh = blockIdx.z, h = bh & (NH_ - 1);
    const int i0 = blockIdx.y * 64, m0 = blockIdx.x * 128;
    // band cull: needed m in [321-i0, 767-i0]
    if (m0 + 127 < 321 - i0 || m0 > 767 - i0) return;

    __shared__ unsigned short Rs[128 * LDT];
    __shared__ unsigned short Ts[64 * 136];
    const int tid = threadIdx.x, w = tid >> 6, lane = tid & 63;
    const int quad = lane >> 4, lm = lane & 15;

    #pragma unroll
    for (int it = 0; it < 4; ++it) {           // stage rp tile 128x64
        const int chunk = it * 256 + tid;
        const int row = chunk >> 3, c8 = chunk & 7;
        *(bf16x8*)&Rs[row * LDT + c8 * 8] =
            *(const bf16x8*)(rp + (size_t)(m0 + row) * 512 + h * 64 + c8 * 8);
    }
    const unsigned short* qrow = qv + (size_t)(bh * L_ + i0 + w * 16 + lm) * DH_;
    const bf16x8 a0 = *(const bf16x8*)(qrow + quad * 8);
    const bf16x8 a1 = *(const bf16x8*)(qrow + 32 + quad * 8);
    __syncthreads();

    #pragma unroll
    for (int ns = 0; ns < 8; ++ns) {
        f32x4 acc = {};
        const bf16x8 b0 = *(const bf16x8*)&Rs[(ns * 16 + lm) * LDT + quad * 8];
        const bf16x8 b1 = *(const bf16x8*)&Rs[(ns * 16 + lm) * LDT + 32 + quad * 8];
        acc = MFMA_BF16(a0, b0, acc, 0, 0, 0);
        acc = MFMA_BF16(a1, b1, acc, 0, 0, 0);
        #pragma unroll
        for (int reg = 0; reg < 4; ++reg)
            Ts[(w * 16 + quad * 4 + reg) * 136 + ns * 16 + lm] = f2bf(acc[reg]);
    }
    __syncthreads();

    // shifted write: 4 threads per i-row, 32 m-cols each; j = m + i - 384
    const int r = tid >> 2, cb = (tid & 3) * 32;
    const int i = i0 + r;
    const int jstart = m0 + i - 384;
    unsigned short* orow = Btb + (size_t)(bh * L_ + i) * L_;
    #pragma unroll
    for (int s = 0; s < 32; ++s) {
        const int mcol = cb + s;
        const int j = jstart + mcol;
        if ((unsigned)j < (unsigned)L_) orow[j] = Ts[r * 136 + mcol];
    }
}

// ---------------------------------------------------------------------------
// Fused attention per (bh, 32-row i-tile): S = qu.k^T + Btb (scale prefolded),
// mask, softmax, P bf16, O = P@v via vT. O written bf16 token-major.
// ---------------------------------------------------------------------------
#define SSTR 401
#define PSTR 392
__global__ __launch_bounds__(256) void attn_fused(
    const unsigned short* __restrict__ qu, const unsigned short* __restrict__ kbf,
    const unsigned short* __restrict__ vT, const unsigned short* __restrict__ Btb,
    const int* __restrict__ seq_len, unsigned short* __restrict__ Obf) {
    __shared__ float S[32 * SSTR];
    __shared__ unsigned short P[32 * PSTR];
    const int lane = threadIdx.x & 63, wv = threadIdx.x >> 6;
    const int quad = lane >> 4, lm = lane & 15;
    const int bh = blockIdx.y, b = bh >> 3, h = bh & 7;
    const int i0 = blockIdx.x * 32;
    const int sl = seq_len[b];
    const int msub = wv & 1, nh = wv >> 1;

    {   // phase 1: scores
        const int i_fr = i0 + msub * 16 + lm;
        const unsigned short* qrow = qu + (size_t)(bh * L_ + i_fr) * DH_;
        const bf16x8 a0 = *(const bf16x8*)(qrow + quad * 8);
        const bf16x8 a1 = *(const bf16x8*)(qrow + 32 + quad * 8);
        f32x4 acc[12] = {};
        #pragma unroll
        for (int ns = 0; ns < 12; ++ns) {
            const int j = nh * 192 + ns * 16 + lm;
            const unsigned short* krow = kbf + (size_t)(bh * L_ + j) * DH_;
            acc[ns] = MFMA_BF16(a0, *(const bf16x8*)(krow + quad * 8), acc[ns], 0, 0, 0);
            acc[ns] = MFMA_BF16(a1, *(const bf16x8*)(krow + 32 + quad * 8), acc[ns], 0, 0, 0);
        }
        #pragma unroll
        for (int ns = 0; ns < 12; ++ns) {
            #pragma unroll
            for (int reg = 0; reg < 4; ++reg) {
                const int il = msub * 16 + quad * 4 + reg;
                const int i = i0 + il;
                const int j = nh * 192 + ns * 16 + lm;
                float val = -1e30f;
                if (j < sl)
                    val = acc[ns][reg] + bf2f(Btb[(size_t)(bh * L_ + i) * L_ + j]);
                S[il * SSTR + j] = val;
            }
        }
    }
    __syncthreads();

    {   // phase 2: row softmax (8 threads per row)
        const int row = threadIdx.x >> 3, sub = threadIdx.x & 7;
        float mx = -1e30f;
        for (int t = sub; t < L_; t += 8) mx = fmaxf(mx, S[row * SSTR + t]);
        #pragma unroll
        for (int o = 1; o < 8; o <<= 1) mx = fmaxf(mx, __shfl_xor(mx, o, 8));
        float sum = 0.f;
        for (int t = sub; t < L_; t += 8) {
            const float e = __expf(S[row * SSTR + t] - mx);
            S[row * SSTR + t] = e;
            sum += e;
        }
        #pragma unroll
        for (int o = 1; o < 8; o <<= 1) sum += __shfl_xor(sum, o, 8);
        const float inv = 1.f / sum;
        for (int t = sub; t < L_; t += 8)
            P[row * PSTR + t] = f2bf(S[row * SSTR + t] * inv);
    }
    __syncthreads();

    {   // phase 3: O = P @ v
        const int pr = msub * 16 + lm;
        f32x4 oacc[2] = {};
        #pragma unroll
        for (int kc = 0; kc < 12; ++kc) {
            const bf16x8 af = *(const bf16x8*)&P[pr * PSTR + kc * 32 + quad * 8];
            #pragma unroll
            for (int t = 0; t < 2; ++t) {
                const int n = nh * 32 + t * 16 + lm;
                const unsigned short* vrow = vT + (size_t)(bh * DH_ + n) * L_ + kc * 32 + quad * 8;
                oacc[t] = MFMA_BF16(af, *(const bf16x8*)(vrow), oacc[t], 0, 0, 0);
            }
        }
        #pragma unroll
        for (int t = 0; t < 2; ++t) {
            #pragma unroll
            for (int reg = 0; reg < 4; ++reg) {
                const int i = i0 + msub * 16 + quad * 4 + reg;
                const int d = nh * 32 + t * 16 + lm;
                Obf[(size_t)(b * L_ + i) * H_ + h * DH_ + d] = f2bf(oacc[t][reg]);
            }
        }
    }
}

extern "C" void kernel_launch(void* const* d_in, const int* in_sizes, int n_in,
                              void* d_out, int out_size, void* d_ws, size_t ws_size,
                              hipStream_t stream) {
    const float* key    = (const float*)d_in[0];
    const float* query  = (const float*)d_in[1];
    const float* value  = (const float*)d_in[2];
    const int*   seqlen = (const int*)d_in[3];
    const float* pe     = (const float*)d_in[4];
    const float* Wk     = (const float*)d_in[5];
    const float* bk     = (const float*)d_in[6];
    const float* Wq     = (const float*)d_in[7];
    const float* bq     = (const float*)d_in[8];
    const float* Wv     = (const float*)d_in[9];
    const float* bv     = (const float*)d_in[10];
    const float* Wr     = (const float*)d_in[11];
    const float* br     = (const float*)d_in[12];
    const float* u_bias = (const float*)d_in[13];
    const float* v_bias = (const float*)d_in[14];
    const float* Wff    = (const float*)d_in[15];
    const float* bff    = (const float*)d_in[16];

    const size_t nTok  = (size_t)B_ * L_ * H_;   // 1,572,864
    const size_t nW    = (size_t)H_ * H_;        // 262,144
    const size_t nPe   = (size_t)RRM * H_;       // 393,216
    unsigned short* p  = (unsigned short*)d_ws;
    unsigned short* qbf  = p; p += nTok;         // reused as Obf after gemm_proj
    unsigned short* kin  = p; p += nTok;
    unsigned short* vin  = p; p += nTok;
    unsigned short* pebf = p; p += nPe;
    unsigned short* Wqb  = p; p += nW;
    unsigned short* Wkb  = p; p += nW;
    unsigned short* Wvb  = p; p += nW;
    unsigned short* Wrb  = p; p += nW;
    unsigned short* Wffb = p; p += nW;
    unsigned short* qu   = p; p += nTok;
    unsigned short* qv   = p; p += nTok;
    unsigned short* kb   = p; p += nTok;
    unsigned short* vT   = p; p += nTok;
    unsigned short* rp   = p; p += nPe;
    unsigned short* Btb  = p; p += (size_t)B_ * NH_ * L_ * L_;  // 9.4M
    unsigned short* Obf  = qbf;                  // alias (same size, disjoint lifetime)

    CvtArgs ca;
    ca.src[0] = query;  ca.dst[0] = qbf;  ca.nchunks[0] = 1536;
    ca.src[1] = key;    ca.dst[1] = kin;  ca.nchunks[1] = 1536;
    ca.src[2] = value;  ca.dst[2] = vin;  ca.nchunks[2] = 1536;
    ca.src[3] = pe;     ca.dst[3] = pebf; ca.nchunks[3] = 384;   // first 768 rows
    ca.src[4] = Wq;     ca.dst[4] = Wqb;  ca.nchunks[4] = 256;
    ca.src[5] = Wk;     ca.dst[5] = Wkb;  ca.nchunks[5] = 256;
    ca.src[6] = Wv;     ca.dst[6] = Wvb;  ca.nchunks[6] = 256;
    ca.src[7] = Wr;     ca.dst[7] = Wrb;  ca.nchunks[7] = 256;
    ca.src[8] = Wff;    ca.dst[8] = Wffb; ca.nchunks[8] = 256;
    cvt_kernel<<<6272, 256, 0, stream>>>(ca);

    gemm_nt<false><<<dim3(8, 48, 4), 256, 0, stream>>>(
        qbf, kin, vin, pebf, Wqb, Wkb, Wvb, Wrb, bq, bk, bv, br,
        u_bias, v_bias, qu, qv, kb, vT, rp, nullptr);

    btshift_kernel<<<dim3(6, 6, 64), 256, 0, stream>>>(qv, rp, Btb);

    attn_fused<<<dim3(L_ / 32, B_ * NH_), 256, 0, stream>>>(qu, kb, vT, Btb, seqlen, Obf);

    gemm_nt<true><<<dim3(8, 48, 1), 256, 0, stream>>>(
        Obf, nullptr, nullptr, nullptr, Wffb, nullptr, nullptr, nullptr,
        bff, nullptr, nullptr, nullptr, nullptr, nullptr,
        nullptr, nullptr, nullptr, nullptr, nullptr, (float*)d_out);
}

// Round 5
// 161.880 us; speedup vs baseline: 11.1071x; 1.4144x over previous
//
#include <hip/hip_runtime.h>
#include <hip/hip_bf16.h>

#define B_  8
#define L_  384
#define H_  512
#define NH_ 8
#define DH_ 64
#define RRM 768            // rproj rows computed; band uses [1,767]; +1 pad row

typedef short bf16x8 __attribute__((ext_vector_type(8)));
typedef float f32x4  __attribute__((ext_vector_type(4)));
#define MFMA_BF16 __builtin_amdgcn_mfma_f32_16x16x32_bf16

static __device__ __forceinline__ unsigned short f2bf(float f) {
    unsigned u = __builtin_bit_cast(unsigned, f);
    u += 0x7fffu + ((u >> 16) & 1u);           // RNE
    return (unsigned short)(u >> 16);
}
static __device__ __forceinline__ float bf2f(unsigned short s) {
    unsigned u = ((unsigned)s) << 16;
    return __builtin_bit_cast(float, u);
}

// ---------------------------------------------------------------------------
// fp32 -> bf16 bulk convert. chunk = 1024 elems (256 thr x 4); regions listed
// in CvtArgs; every region size is a multiple of 1024 (no tails).
// ---------------------------------------------------------------------------
struct CvtArgs {
    const float* src[9];
    unsigned short* dst[9];
    int nchunks[9];
};
__global__ __launch_bounds__(256) void cvt_kernel(CvtArgs a) {
    int chunk = blockIdx.x;
    int r = 0;
    while (r < 8 && chunk >= a.nchunks[r]) { chunk -= a.nchunks[r]; r++; }
    const float4 v = ((const float4*)a.src[r])[chunk * 256 + threadIdx.x];
    ushort4 o;
    o.x = f2bf(v.x); o.y = f2bf(v.y); o.z = f2bf(v.z); o.w = f2bf(v.w);
    ((ushort4*)a.dst[r])[chunk * 256 + threadIdx.x] = o;
}

// ---------------------------------------------------------------------------
// bf16 NT GEMM, K=512, tile 64x64, BK=64, double-buffered LDS, 4 waves (2x2).
// IS_FF=false: grid (8, 48, 4); z selects {q,k,v,pe} with per-mode epilogues.
// IS_FF=true : grid (8, 48, 1); A=Obf, out fp32 d_out.
// ---------------------------------------------------------------------------
#define LDT 72   // padded LDS row stride (ushorts)

template <bool IS_FF>
__global__ __launch_bounds__(256) void gemm_nt(
    const unsigned short* __restrict__ A0, const unsigned short* __restrict__ A1,
    const unsigned short* __restrict__ A2, const unsigned short* __restrict__ A3,
    const unsigned short* __restrict__ W0, const unsigned short* __restrict__ W1,
    const unsigned short* __restrict__ W2, const unsigned short* __restrict__ W3,
    const float* __restrict__ b0, const float* __restrict__ b1,
    const float* __restrict__ b2, const float* __restrict__ b3,
    const float* __restrict__ ub, const float* __restrict__ vbias,
    unsigned short* __restrict__ qu, unsigned short* __restrict__ qv,
    unsigned short* __restrict__ kb, unsigned short* __restrict__ vT,
    unsigned short* __restrict__ rp, float* __restrict__ ff) {

    const int z = IS_FF ? 4 : blockIdx.z;
    if (!IS_FF && z == 3 && blockIdx.y >= 12) return;   // pe has 768 rows
    const unsigned short* A = IS_FF ? A0 : (z == 0 ? A0 : z == 1 ? A1 : z == 2 ? A2 : A3);
    const unsigned short* W = IS_FF ? W0 : (z == 0 ? W0 : z == 1 ? W1 : z == 2 ? W2 : W3);
    const float* bias       = IS_FF ? b0 : (z == 0 ? b0 : z == 1 ? b1 : z == 2 ? b2 : b3);

    __shared__ unsigned short As[2][64 * LDT];
    __shared__ unsigned short Bs[2][64 * LDT];

    const int tid = threadIdx.x;
    const int w = tid >> 6, lane = tid & 63;
    const int quad = lane >> 4, lm = lane & 15;
    const int l8r = lane >> 3, l8c = lane & 7;
    const int wr = (w & 1) * 32, wc = (w >> 1) * 32;

    const unsigned short* ag = A + (size_t)(blockIdx.y * 64 + w * 16 + l8r) * 512 + l8c * 8;
    const unsigned short* wg = W + (size_t)(blockIdx.x * 64 + w * 16 + l8r) * 512 + l8c * 8;
    const int soff = (w * 16 + l8r) * LDT + l8c * 8;

    bf16x8 pa0 = *(const bf16x8*)(ag);
    bf16x8 pa1 = *(const bf16x8*)(ag + 8 * 512);
    bf16x8 pb0 = *(const bf16x8*)(wg);
    bf16x8 pb1 = *(const bf16x8*)(wg + 8 * 512);
    *(bf16x8*)&As[0][soff]            = pa0;
    *(bf16x8*)&As[0][soff + 8 * LDT]  = pa1;
    *(bf16x8*)&Bs[0][soff]            = pb0;
    *(bf16x8*)&Bs[0][soff + 8 * LDT]  = pb1;

    f32x4 acc[2][2] = {};
    for (int kc = 0; kc < 8; ++kc) {
        __syncthreads();
        const int buf = kc & 1;
        if (kc < 7) {
            const int k0 = (kc + 1) * 64;
            pa0 = *(const bf16x8*)(ag + k0);
            pa1 = *(const bf16x8*)(ag + k0 + 8 * 512);
            pb0 = *(const bf16x8*)(wg + k0);
            pb1 = *(const bf16x8*)(wg + k0 + 8 * 512);
        }
        #pragma unroll
        for (int ks = 0; ks < 2; ++ks) {
            bf16x8 a0 = *(const bf16x8*)&As[buf][(wr + lm) * LDT + ks * 32 + quad * 8];
            bf16x8 a1 = *(const bf16x8*)&As[buf][(wr + 16 + lm) * LDT + ks * 32 + quad * 8];
            bf16x8 w0 = *(const bf16x8*)&Bs[buf][(wc + lm) * LDT + ks * 32 + quad * 8];
            bf16x8 w1 = *(const bf16x8*)&Bs[buf][(wc + 16 + lm) * LDT + ks * 32 + quad * 8];
            acc[0][0] = MFMA_BF16(a0, w0, acc[0][0], 0, 0, 0);
            acc[0][1] = MFMA_BF16(a0, w1, acc[0][1], 0, 0, 0);
            acc[1][0] = MFMA_BF16(a1, w0, acc[1][0], 0, 0, 0);
            acc[1][1] = MFMA_BF16(a1, w1, acc[1][1], 0, 0, 0);
        }
        if (kc < 7) {
            const int nb = buf ^ 1;
            *(bf16x8*)&As[nb][soff]           = pa0;
            *(bf16x8*)&As[nb][soff + 8 * LDT] = pa1;
            *(bf16x8*)&Bs[nb][soff]           = pb0;
            *(bf16x8*)&Bs[nb][soff + 8 * LDT] = pb1;
        }
    }

    #pragma unroll
    for (int si = 0; si < 2; ++si) {
        #pragma unroll
        for (int sj = 0; sj < 2; ++sj) {
            #pragma unroll
            for (int reg = 0; reg < 4; ++reg) {
                const int r = blockIdx.y * 64 + wr + si * 16 + quad * 4 + reg;
                const int c = blockIdx.x * 64 + wc + sj * 16 + lm;
                const float val = acc[si][sj][reg] + bias[c];
                if (IS_FF) {
                    ff[r * 512 + c] = val;
                } else if (z == 0) {
                    const int bb = r / L_, ii = r - bb * L_;
                    const int h = c >> 6, d = c & 63;
                    const int idx = ((bb * NH_ + h) * L_ + ii) * DH_ + d;
                    qu[idx] = f2bf((val + ub[c]) * 0.125f);     // pow2 scale: exact
                    qv[idx] = f2bf((val + vbias[c]) * 0.125f);
                } else if (z == 1) {
                    const int bb = r / L_, ii = r - bb * L_;
                    const int h = c >> 6, d = c & 63;
                    kb[((bb * NH_ + h) * L_ + ii) * DH_ + d] = f2bf(val);
                } else if (z == 2) {
                    const int bb = r / L_, ii = r - bb * L_;
                    const int h = c >> 6, d = c & 63;
                    vT[((bb * NH_ + h) * DH_ + d) * L_ + ii] = f2bf(val);
                } else {
                    rp[r * 512 + c] = f2bf(val);
                }
            }
        }
    }
}

// ---------------------------------------------------------------------------
// Fully fused attention per (bh, 32-row i-tile):
//   Bt tile  = qv . rp[m_lo + n]   (MFMA, bf16 -> LDS, shifted-read later)
//   S        = qu . k^T + Bt(shift), mask          (registers)
//   softmax  : register max/sum, shfl over lm, tiny LDS cross-wave combine
//   P (bf16) -> LDS (reuses Bt buffer), O = P @ v via vT (MFMA), O bf16.
// ---------------------------------------------------------------------------
#define BTSTR 424   // LDS row stride for Bt/P tile (ushorts), 848 B (16B mult)
__global__ __launch_bounds__(256) void attn_fused(
    const unsigned short* __restrict__ qu, const unsigned short* __restrict__ qv,
    const unsigned short* __restrict__ kbf, const unsigned short* __restrict__ vT,
    const unsigned short* __restrict__ rp, const int* __restrict__ seq_len,
    unsigned short* __restrict__ Obf) {
    __shared__ __align__(16) unsigned short BtP[32 * BTSTR];
    __shared__ float mx_red[32][2];
    __shared__ float sm_red[32][2];
    const int lane = threadIdx.x & 63, wv = threadIdx.x >> 6;
    const int quad = lane >> 4, lm = lane & 15;
    const int bh = blockIdx.y, b = bh >> 3, h = bh & 7;
    const int i0 = blockIdx.x * 32;
    const int sl = seq_len[b];
    const int msub = wv & 1, nh = wv >> 1;
    const int m_lo = 353 - i0;                 // rp window start
    const int i_fr = i0 + msub * 16 + lm;

    // ---- Bt tile: Bt[il][n] = qv[i0+il] . rp[m_lo+n], n in [0,416) ----
    {
        const unsigned short* qvr = qv + (size_t)(bh * L_ + i_fr) * DH_;
        const bf16x8 av0 = *(const bf16x8*)(qvr + quad * 8);
        const bf16x8 av1 = *(const bf16x8*)(qvr + 32 + quad * 8);
        #pragma unroll
        for (int ns = 0; ns < 13; ++ns) {
            const int n = nh * 208 + ns * 16 + lm;
            const unsigned short* rrow = rp + (size_t)(m_lo + n) * 512 + h * 64;
            f32x4 bacc = {};
            bacc = MFMA_BF16(av0, *(const bf16x8*)(rrow + quad * 8), bacc, 0, 0, 0);
            bacc = MFMA_BF16(av1, *(const bf16x8*)(rrow + 32 + quad * 8), bacc, 0, 0, 0);
            #pragma unroll
            for (int reg = 0; reg < 4; ++reg) {
                const int il = msub * 16 + quad * 4 + reg;
                BtP[il * BTSTR + n] = f2bf(bacc[reg]);
            }
        }
    }
    const unsigned short* qur = qu + (size_t)(bh * L_ + i_fr) * DH_;
    const bf16x8 au0 = *(const bf16x8*)(qur + quad * 8);
    const bf16x8 au1 = *(const bf16x8*)(qur + 32 + quad * 8);
    __syncthreads();

    // ---- QK scores + Bt shift-add + mask (in registers) ----
    f32x4 sc[12];
    #pragma unroll
    for (int ns = 0; ns < 12; ++ns) {
        const int j = nh * 192 + ns * 16 + lm;
        const unsigned short* krow = kbf + (size_t)(bh * L_ + j) * DH_;
        f32x4 a = {};
        a = MFMA_BF16(au0, *(const bf16x8*)(krow + quad * 8), a, 0, 0, 0);
        a = MFMA_BF16(au1, *(const bf16x8*)(krow + 32 + quad * 8), a, 0, 0, 0);
        sc[ns] = a;
    }
    const int jbase = nh * 192 + lm;
    #pragma unroll
    for (int ns = 0; ns < 12; ++ns) {
        const int j = jbase + ns * 16;
        #pragma unroll
        for (int reg = 0; reg < 4; ++reg) {
            const int il = msub * 16 + quad * 4 + reg;
            float val = -1e30f;
            if (j < sl) val = sc[ns][reg] + bf2f(BtP[il * BTSTR + (j - il + 31)]);
            sc[ns][reg] = val;
        }
    }

    // ---- register softmax ----
    const int il0 = msub * 16 + quad * 4;
    float mx4[4], sm4[4], inv4[4];
    #pragma unroll
    for (int reg = 0; reg < 4; ++reg) {
        float m = sc[0][reg];
        #pragma unroll
        for (int ns = 1; ns < 12; ++ns) m = fmaxf(m, sc[ns][reg]);
        #pragma unroll
        for (int o = 1; o < 16; o <<= 1) m = fmaxf(m, __shfl_xor(m, o));
        mx4[reg] = m;
    }
    if (lm == 0) {
        #pragma unroll
        for (int reg = 0; reg < 4; ++reg) mx_red[il0 + reg][nh] = mx4[reg];
    }
    __syncthreads();
    #pragma unroll
    for (int reg = 0; reg < 4; ++reg)
        mx4[reg] = fmaxf(mx_red[il0 + reg][0], mx_red[il0 + reg][1]);
    #pragma unroll
    for (int reg = 0; reg < 4; ++reg) sm4[reg] = 0.f;
    #pragma unroll
    for (int ns = 0; ns < 12; ++ns) {
        #pragma unroll
        for (int reg = 0; reg < 4; ++reg) {
            const float e = __expf(sc[ns][reg] - mx4[reg]);
            sc[ns][reg] = e;
            sm4[reg] += e;
        }
    }
    #pragma unroll
    for (int reg = 0; reg < 4; ++reg) {
        float s = sm4[reg];
        #pragma unroll
        for (int o = 1; o < 16; o <<= 1) s += __shfl_xor(s, o);
        sm4[reg] = s;
    }
    if (lm == 0) {
        #pragma unroll
        for (int reg = 0; reg < 4; ++reg) sm_red[il0 + reg][nh] = sm4[reg];
    }
    __syncthreads();
    #pragma unroll
    for (int reg = 0; reg < 4; ++reg)
        inv4[reg] = 1.f / (sm_red[il0 + reg][0] + sm_red[il0 + reg][1]);

    // ---- P (bf16) into LDS (Bt buffer is dead now) ----
    #pragma unroll
    for (int ns = 0; ns < 12; ++ns) {
        const int j = jbase + ns * 16;
        #pragma unroll
        for (int reg = 0; reg < 4; ++reg)
            BtP[(il0 + reg) * BTSTR + j] = f2bf(sc[ns][reg] * inv4[reg]);
    }
    __syncthreads();

    // ---- O = P @ v via MFMA (wave: 16 rows x 32 d) ----
    {
        const int pr = msub * 16 + lm;
        f32x4 oacc[2] = {};
        #pragma unroll
        for (int kc = 0; kc < 12; ++kc) {
            const bf16x8 af = *(const bf16x8*)&BtP[pr * BTSTR + kc * 32 + quad * 8];
            #pragma unroll
            for (int t = 0; t < 2; ++t) {
                const int n = nh * 32 + t * 16 + lm;
                const unsigned short* vrow = vT + (size_t)(bh * DH_ + n) * L_ + kc * 32 + quad * 8;
                oacc[t] = MFMA_BF16(af, *(const bf16x8*)(vrow), oacc[t], 0, 0, 0);
            }
        }
        #pragma unroll
        for (int t = 0; t < 2; ++t) {
            #pragma unroll
            for (int reg = 0; reg < 4; ++reg) {
                const int i = i0 + msub * 16 + quad * 4 + reg;
                const int d = nh * 32 + t * 16 + lm;
                Obf[(size_t)(b * L_ + i) * H_ + h * DH_ + d] = f2bf(oacc[t][reg]);
            }
        }
    }
}

extern "C" void kernel_launch(void* const* d_in, const int* in_sizes, int n_in,
                              void* d_out, int out_size, void* d_ws, size_t ws_size,
                              hipStream_t stream) {
    const float* key    = (const float*)d_in[0];
    const float* query  = (const float*)d_in[1];
    const float* value  = (const float*)d_in[2];
    const int*   seqlen = (const int*)d_in[3];
    const float* pe     = (const float*)d_in[4];
    const float* Wk     = (const float*)d_in[5];
    const float* bk     = (const float*)d_in[6];
    const float* Wq     = (const float*)d_in[7];
    const float* bq     = (const float*)d_in[8];
    const float* Wv     = (const float*)d_in[9];
    const float* bv     = (const float*)d_in[10];
    const float* Wr     = (const float*)d_in[11];
    const float* br     = (const float*)d_in[12];
    const float* u_bias = (const float*)d_in[13];
    const float* v_bias = (const float*)d_in[14];
    const float* Wff    = (const float*)d_in[15];
    const float* bff    = (const float*)d_in[16];

    const size_t nTok  = (size_t)B_ * L_ * H_;   // 1,572,864
    const size_t nW    = (size_t)H_ * H_;        // 262,144
    const size_t nPe   = (size_t)RRM * H_;       // 393,216
    unsigned short* p  = (unsigned short*)d_ws;
    unsigned short* qbf  = p; p += nTok;         // reused as Obf after projections
    unsigned short* kin  = p; p += nTok;
    unsigned short* vin  = p; p += nTok;
    unsigned short* pebf = p; p += nPe;
    unsigned short* Wqb  = p; p += nW;
    unsigned short* Wkb  = p; p += nW;
    unsigned short* Wvb  = p; p += nW;
    unsigned short* Wrb  = p; p += nW;
    unsigned short* Wffb = p; p += nW;
    unsigned short* qu   = p; p += nTok;
    unsigned short* qv   = p; p += nTok;
    unsigned short* kb   = p; p += nTok;
    unsigned short* vT   = p; p += nTok;
    unsigned short* rp   = p; p += nPe + 512;    // +1 pad row (corner t=415 read)
    unsigned short* Obf  = qbf;                  // alias (disjoint lifetime)

    CvtArgs ca;
    ca.src[0] = query;  ca.dst[0] = qbf;  ca.nchunks[0] = 1536;
    ca.src[1] = key;    ca.dst[1] = kin;  ca.nchunks[1] = 1536;
    ca.src[2] = value;  ca.dst[2] = vin;  ca.nchunks[2] = 1536;
    ca.src[3] = pe;     ca.dst[3] = pebf; ca.nchunks[3] = 384;   // first 768 rows
    ca.src[4] = Wq;     ca.dst[4] = Wqb;  ca.nchunks[4] = 256;
    ca.src[5] = Wk;     ca.dst[5] = Wkb;  ca.nchunks[5] = 256;
    ca.src[6] = Wv;     ca.dst[6] = Wvb;  ca.nchunks[6] = 256;
    ca.src[7] = Wr;     ca.dst[7] = Wrb;  ca.nchunks[7] = 256;
    ca.src[8] = Wff;    ca.dst[8] = Wffb; ca.nchunks[8] = 256;
    cvt_kernel<<<6272, 256, 0, stream>>>(ca);

    gemm_nt<false><<<dim3(8, 48, 4), 256, 0, stream>>>(
        qbf, kin, vin, pebf, Wqb, Wkb, Wvb, Wrb, bq, bk, bv, br,
        u_bias, v_bias, qu, qv, kb, vT, rp, nullptr);

    attn_fused<<<dim3(L_ / 32, B_ * NH_), 256, 0, stream>>>(
        qu, qv, kb, vT, rp, seqlen, Obf);

    gemm_nt<true><<<dim3(8, 48, 1), 256, 0, stream>>>(
        Obf, nullptr, nullptr, nullptr, Wffb, nullptr, nullptr, nullptr,
        bff, nullptr, nullptr, nullptr, nullptr, nullptr,
        nullptr, nullptr, nullptr, nullptr, nullptr, (float*)d_out);
}

// Round 8
// 161.519 us; speedup vs baseline: 11.1319x; 1.0022x over previous
//
#include <hip/hip_runtime.h>
#include <hip/hip_bf16.h>

#define B_  8
#define L_  384
#define H_  512
#define NH_ 8
#define DH_ 64
#define RRM 768            // rproj rows computed; band uses [1,767]; +1 pad row

typedef short bf16x8 __attribute__((ext_vector_type(8)));
typedef float f32x4  __attribute__((ext_vector_type(4)));
#define MFMA_BF16 __builtin_amdgcn_mfma_f32_16x16x32_bf16

static __device__ __forceinline__ unsigned short f2bf(float f) {
    unsigned u = __builtin_bit_cast(unsigned, f);
    u += 0x7fffu + ((u >> 16) & 1u);           // RNE
    return (unsigned short)(u >> 16);
}
static __device__ __forceinline__ float bf2f(unsigned short s) {
    unsigned u = ((unsigned)s) << 16;
    return __builtin_bit_cast(float, u);
}
static __device__ __forceinline__ unsigned pack2(float lo, float hi) {
    return (unsigned)f2bf(lo) | ((unsigned)f2bf(hi) << 16);
}
// 8 fp32 -> 8 bf16 (RNE) -> one 16B LDS store
static __device__ __forceinline__ void cvt_store8(unsigned short* dst, float4 a, float4 b) {
    uint4 o;
    o.x = pack2(a.x, a.y);
    o.y = pack2(a.z, a.w);
    o.z = pack2(b.x, b.y);
    o.w = pack2(b.z, b.w);
    *(uint4*)dst = o;
}

// ---------------------------------------------------------------------------
// bf16 MFMA NT GEMM with fp32 inputs converted during LDS staging.
// K=512, tile 64x64, BK=64, double-buffered LDS, 4 waves (2x2 of 32x32).
// IS_FF=false: grid (8, 48, 4); z selects {q,k,v,pe}; A,W fp32.
// IS_FF=true : grid (8, 48, 1); A=Obf (bf16), W=Wff fp32; out fp32 d_out.
// ---------------------------------------------------------------------------
#define LDT 72   // padded LDS row stride (ushorts)

template <bool IS_FF>
__global__ __launch_bounds__(256) void gemm_nt(
    const float* __restrict__ A0f, const float* __restrict__ A1f,
    const float* __restrict__ A2f, const float* __restrict__ A3f,
    const unsigned short* __restrict__ Abf,
    const float* __restrict__ W0, const float* __restrict__ W1,
    const float* __restrict__ W2, const float* __restrict__ W3,
    const float* __restrict__ W4,
    const float* __restrict__ b0, const float* __restrict__ b1,
    const float* __restrict__ b2, const float* __restrict__ b3,
    const float* __restrict__ b4,
    const float* __restrict__ ub, const float* __restrict__ vbias,
    unsigned short* __restrict__ qu, unsigned short* __restrict__ qv,
    unsigned short* __restrict__ kb, unsigned short* __restrict__ vT,
    unsigned short* __restrict__ rp, float* __restrict__ ff) {

    const int z = IS_FF ? 4 : blockIdx.z;
    if (!IS_FF && z == 3 && blockIdx.y >= 12) return;   // pe: 768 rows only
    const float* Af   = IS_FF ? nullptr : (z == 0 ? A0f : z == 1 ? A1f : z == 2 ? A2f : A3f);
    const float* W    = IS_FF ? W4 : (z == 0 ? W0 : z == 1 ? W1 : z == 2 ? W2 : W3);
    const float* bias = IS_FF ? b4 : (z == 0 ? b0 : z == 1 ? b1 : z == 2 ? b2 : b3);

    __shared__ unsigned short As[2][64 * LDT];
    __shared__ unsigned short Bs[2][64 * LDT];

    const int tid = threadIdx.x;
    const int w = tid >> 6, lane = tid & 63;
    const int quad = lane >> 4, lm = lane & 15;
    const int l8r = lane >> 3, l8c = lane & 7;
    const int wr = (w & 1) * 32, wc = (w >> 1) * 32;

    const size_t arow = (size_t)blockIdx.y * 64 + w * 16 + l8r;
    const size_t wrow = (size_t)blockIdx.x * 64 + w * 16 + l8r;
    const float* agf = IS_FF ? nullptr : Af + arow * 512 + l8c * 8;
    const unsigned short* agb = IS_FF ? Abf + arow * 512 + l8c * 8 : nullptr;
    const float* wgf = W + wrow * 512 + l8c * 8;
    const int soff = (w * 16 + l8r) * LDT + l8c * 8;

    float4 pw0, pw1, pw2, pw3;
    float4 pa0, pa1, pa2, pa3;
    bf16x8 pab0, pab1;

    // prologue: fetch + stage chunk 0
    pw0 = *(const float4*)(wgf);           pw1 = *(const float4*)(wgf + 4);
    pw2 = *(const float4*)(wgf + 8 * 512); pw3 = *(const float4*)(wgf + 8 * 512 + 4);
    if constexpr (!IS_FF) {
        pa0 = *(const float4*)(agf);           pa1 = *(const float4*)(agf + 4);
        pa2 = *(const float4*)(agf + 8 * 512); pa3 = *(const float4*)(agf + 8 * 512 + 4);
        cvt_store8(&As[0][soff], pa0, pa1);
        cvt_store8(&As[0][soff + 8 * LDT], pa2, pa3);
    } else {
        pab0 = *(const bf16x8*)(agb);
        pab1 = *(const bf16x8*)(agb + 8 * 512);
        *(bf16x8*)&As[0][soff] = pab0;
        *(bf16x8*)&As[0][soff + 8 * LDT] = pab1;
    }
    cvt_store8(&Bs[0][soff], pw0, pw1);
    cvt_store8(&Bs[0][soff + 8 * LDT], pw2, pw3);

    f32x4 acc[2][2] = {};
    for (int kc = 0; kc < 8; ++kc) {
        __syncthreads();
        const int buf = kc & 1;
        if (kc < 7) {                          // prefetch next chunk into regs
            const int k0 = (kc + 1) * 64;
            pw0 = *(const float4*)(wgf + k0);           pw1 = *(const float4*)(wgf + k0 + 4);
            pw2 = *(const float4*)(wgf + k0 + 8 * 512); pw3 = *(const float4*)(wgf + k0 + 8 * 512 + 4);
            if constexpr (!IS_FF) {
                pa0 = *(const float4*)(agf + k0);           pa1 = *(const float4*)(agf + k0 + 4);
                pa2 = *(const float4*)(agf + k0 + 8 * 512); pa3 = *(const float4*)(agf + k0 + 8 * 512 + 4);
            } else {
                pab0 = *(const bf16x8*)(agb + k0);
                pab1 = *(const bf16x8*)(agb + k0 + 8 * 512);
            }
        }
        #pragma unroll
        for (int ks = 0; ks < 2; ++ks) {
            bf16x8 a0 = *(const bf16x8*)&As[buf][(wr + lm) * LDT + ks * 32 + quad * 8];
            bf16x8 a1 = *(const bf16x8*)&As[buf][(wr + 16 + lm) * LDT + ks * 32 + quad * 8];
            bf16x8 w0 = *(const bf16x8*)&Bs[buf][(wc + lm) * LDT + ks * 32 + quad * 8];
            bf16x8 w1 = *(const bf16x8*)&Bs[buf][(wc + 16 + lm) * LDT + ks * 32 + quad * 8];
            acc[0][0] = MFMA_BF16(a0, w0, acc[0][0], 0, 0, 0);
            acc[0][1] = MFMA_BF16(a0, w1, acc[0][1], 0, 0, 0);
            acc[1][0] = MFMA_BF16(a1, w0, acc[1][0], 0, 0, 0);
            acc[1][1] = MFMA_BF16(a1, w1, acc[1][1], 0, 0, 0);
        }
        if (kc < 7) {                          // stage prefetch into other buffer
            const int nb = buf ^ 1;
            if constexpr (!IS_FF) {
                cvt_store8(&As[nb][soff], pa0, pa1);
                cvt_store8(&As[nb][soff + 8 * LDT], pa2, pa3);
            } else {
                *(bf16x8*)&As[nb][soff] = pab0;
                *(bf16x8*)&As[nb][soff + 8 * LDT] = pab1;
            }
            cvt_store8(&Bs[nb][soff], pw0, pw1);
            cvt_store8(&Bs[nb][soff + 8 * LDT], pw2, pw3);
        }
    }

    #pragma unroll
    for (int si = 0; si < 2; ++si) {
        #pragma unroll
        for (int sj = 0; sj < 2; ++sj) {
            #pragma unroll
            for (int reg = 0; reg < 4; ++reg) {
                const int r = blockIdx.y * 64 + wr + si * 16 + quad * 4 + reg;
                const int c = blockIdx.x * 64 + wc + sj * 16 + lm;
                const float val = acc[si][sj][reg] + bias[c];
                if (IS_FF) {
                    ff[r * 512 + c] = val;
                } else if (z == 0) {
                    const int bb = r / L_, ii = r - bb * L_;
                    const int h = c >> 6, d = c & 63;
                    const int idx = ((bb * NH_ + h) * L_ + ii) * DH_ + d;
                    qu[idx] = f2bf((val + ub[c]) * 0.125f);     // pow2 scale: exact
                    qv[idx] = f2bf((val + vbias[c]) * 0.125f);
                } else if (z == 1) {
                    const int bb = r / L_, ii = r - bb * L_;
                    const int h = c >> 6, d = c & 63;
                    kb[((bb * NH_ + h) * L_ + ii) * DH_ + d] = f2bf(val);
                } else if (z == 2) {
                    const int bb = r / L_, ii = r - bb * L_;
                    const int h = c >> 6, d = c & 63;
                    vT[((bb * NH_ + h) * DH_ + d) * L_ + ii] = f2bf(val);
                } else {
                    rp[r * 512 + c] = f2bf(val);
                }
            }
        }
    }
}

// ---------------------------------------------------------------------------
// Fully fused attention per (bh, 32-row i-tile), with seq_len tile skipping:
//   Bt tile  = qv . rp[m_lo + n]   (MFMA, bf16 -> LDS, shifted-read later)
//   S        = qu . k^T + Bt(shift), mask          (registers)
//   softmax  : register max/sum, shfl over lm, tiny LDS cross-wave combine
//   P (bf16) -> LDS (reuses Bt buffer), O = P @ v via vT (MFMA), O bf16.
// ---------------------------------------------------------------------------
#define BTSTR 424   // LDS row stride for Bt/P tile (ushorts), 848 B
__global__ __launch_bounds__(256) void attn_fused(
    const unsigned short* __restrict__ qu, const unsigned short* __restrict__ qv,
    const unsigned short* __restrict__ kbf, const unsigned short* __restrict__ vT,
    const unsigned short* __restrict__ rp, const int* __restrict__ seq_len,
    unsigned short* __restrict__ Obf) {
    __shared__ __align__(16) unsigned short BtP[32 * BTSTR];
    __shared__ float mx_red[32][2];
    __shared__ float sm_red[32][2];
    const int lane = threadIdx.x & 63, wv = threadIdx.x >> 6;
    const int quad = lane >> 4, lm = lane & 15;
    const int bh = blockIdx.y, b = bh >> 3, h = bh & 7;
    const int i0 = blockIdx.x * 32;
    const int sl = seq_len[b];
    const int msub = wv & 1, nh = wv >> 1;
    const int m_lo = 353 - i0;                 // rp window start
    const int i_fr = i0 + msub * 16 + lm;

    // ---- Bt tile: Bt[il][n] = qv[i0+il] . rp[m_lo+n]; skip tiles beyond sl ----
    {
        const unsigned short* qvr = qv + (size_t)(bh * L_ + i_fr) * DH_;
        const bf16x8 av0 = *(const bf16x8*)(qvr + quad * 8);
        const bf16x8 av1 = *(const bf16x8*)(qvr + 32 + quad * 8);
        #pragma unroll
        for (int ns = 0; ns < 13; ++ns) {
            const int ntl = nh * 208 + ns * 16;
            if (ntl <= sl + 30) {              // needed: n = j-il+31 <= sl+30
                const int n = ntl + lm;
                const unsigned short* rrow = rp + (size_t)(m_lo + n) * 512 + h * 64;
                f32x4 bacc = {};
                bacc = MFMA_BF16(av0, *(const bf16x8*)(rrow + quad * 8), bacc, 0, 0, 0);
                bacc = MFMA_BF16(av1, *(const bf16x8*)(rrow + 32 + quad * 8), bacc, 0, 0, 0);
                #pragma unroll
                for (int reg = 0; reg < 4; ++reg) {
                    const int il = msub * 16 + quad * 4 + reg;
                    BtP[il * BTSTR + n] = f2bf(bacc[reg]);
                }
            }
        }
    }
    const unsigned short* qur = qu + (size_t)(bh * L_ + i_fr) * DH_;
    const bf16x8 au0 = *(const bf16x8*)(qur + quad * 8);
    const bf16x8 au1 = *(const bf16x8*)(qur + 32 + quad * 8);
    __syncthreads();

    // ---- QK scores (skip fully-masked tiles) + Bt shift-add + mask ----
    f32x4 sc[12];
    #pragma unroll
    for (int ns = 0; ns < 12; ++ns) {
        const int jt = nh * 192 + ns * 16;
        if (jt < sl) {
            const unsigned short* krow = kbf + (size_t)(bh * L_ + jt + lm) * DH_;
            f32x4 a = {};
            a = MFMA_BF16(au0, *(const bf16x8*)(krow + quad * 8), a, 0, 0, 0);
            a = MFMA_BF16(au1, *(const bf16x8*)(krow + 32 + quad * 8), a, 0, 0, 0);
            sc[ns] = a;
        } else {
            sc[ns] = f32x4{-1e30f, -1e30f, -1e30f, -1e30f};
        }
    }
    const int jbase = nh * 192 + lm;
    #pragma unroll
    for (int ns = 0; ns < 12; ++ns) {
        const int j = jbase + ns * 16;
        #pragma unroll
        for (int reg = 0; reg < 4; ++reg) {
            const int il = msub * 16 + quad * 4 + reg;
            float val = -1e30f;
            if (j < sl) val = sc[ns][reg] + bf2f(BtP[il * BTSTR + (j - il + 31)]);
            sc[ns][reg] = val;
        }
    }

    // ---- register softmax ----
    const int il0 = msub * 16 + quad * 4;
    float mx4[4], sm4[4], inv4[4];
    #pragma unroll
    for (int reg = 0; reg < 4; ++reg) {
        float m = sc[0][reg];
        #pragma unroll
        for (int ns = 1; ns < 12; ++ns) m = fmaxf(m, sc[ns][reg]);
        #pragma unroll
        for (int o = 1; o < 16; o <<= 1) m = fmaxf(m, __shfl_xor(m, o));
        mx4[reg] = m;
    }
    if (lm == 0) {
        #pragma unroll
        for (int reg = 0; reg < 4; ++reg) mx_red[il0 + reg][nh] = mx4[reg];
    }
    __syncthreads();
    #pragma unroll
    for (int reg = 0; reg < 4; ++reg)
        mx4[reg] = fmaxf(mx_red[il0 + reg][0], mx_red[il0 + reg][1]);
    #pragma unroll
    for (int reg = 0; reg < 4; ++reg) sm4[reg] = 0.f;
    #pragma unroll
    for (int ns = 0; ns < 12; ++ns) {
        #pragma unroll
        for (int reg = 0; reg < 4; ++reg) {
            const float e = __expf(sc[ns][reg] - mx4[reg]);
            sc[ns][reg] = e;
            sm4[reg] += e;
        }
    }
    #pragma unroll
    for (int reg = 0; reg < 4; ++reg) {
        float s = sm4[reg];
        #pragma unroll
        for (int o = 1; o < 16; o <<= 1) s += __shfl_xor(s, o);
        sm4[reg] = s;
    }
    if (lm == 0) {
        #pragma unroll
        for (int reg = 0; reg < 4; ++reg) sm_red[il0 + reg][nh] = sm4[reg];
    }
    __syncthreads();
    #pragma unroll
    for (int reg = 0; reg < 4; ++reg)
        inv4[reg] = 1.f / (sm_red[il0 + reg][0] + sm_red[il0 + reg][1]);

    // ---- P (bf16) into LDS (Bt buffer dead now) ----
    #pragma unroll
    for (int ns = 0; ns < 12; ++ns) {
        const int j = jbase + ns * 16;
        #pragma unroll
        for (int reg = 0; reg < 4; ++reg)
            BtP[(il0 + reg) * BTSTR + j] = f2bf(sc[ns][reg] * inv4[reg]);
    }
    __syncthreads();

    // ---- O = P @ v via MFMA; K-loop cut at ceil(sl/32) ----
    {
        const int pr = msub * 16 + lm;
        const int nkc = (sl + 31) >> 5;        // <= 12
        f32x4 oacc[2] = {};
        for (int kc = 0; kc < nkc; ++kc) {
            const bf16x8 af = *(const bf16x8*)&BtP[pr * BTSTR + kc * 32 + quad * 8];
            #pragma unroll
            for (int t = 0; t < 2; ++t) {
                const int n = nh * 32 + t * 16 + lm;
                const unsigned short* vrow = vT + (size_t)(bh * DH_ + n) * L_ + kc * 32 + quad * 8;
                oacc[t] = MFMA_BF16(af, *(const bf16x8*)(vrow), oacc[t], 0, 0, 0);
            }
        }
        #pragma unroll
        for (int t = 0; t < 2; ++t) {
            #pragma unroll
            for (int reg = 0; reg < 4; ++reg) {
                const int i = i0 + msub * 16 + quad * 4 + reg;
                const int d = nh * 32 + t * 16 + lm;
                Obf[(size_t)(b * L_ + i) * H_ + h * DH_ + d] = f2bf(oacc[t][reg]);
            }
        }
    }
}

extern "C" void kernel_launch(void* const* d_in, const int* in_sizes, int n_in,
                              void* d_out, int out_size, void* d_ws, size_t ws_size,
                              hipStream_t stream) {
    const float* key    = (const float*)d_in[0];
    const float* query  = (const float*)d_in[1];
    const float* value  = (const float*)d_in[2];
    const int*   seqlen = (const int*)d_in[3];
    const float* pe     = (const float*)d_in[4];
    const float* Wk     = (const float*)d_in[5];
    const float* bk     = (const float*)d_in[6];
    const float* Wq     = (const float*)d_in[7];
    const float* bq     = (const float*)d_in[8];
    const float* Wv     = (const float*)d_in[9];
    const float* bv     = (const float*)d_in[10];
    const float* Wr     = (const float*)d_in[11];
    const float* br     = (const float*)d_in[12];
    const float* u_bias = (const float*)d_in[13];
    const float* v_bias = (const float*)d_in[14];
    const float* Wff    = (const float*)d_in[15];
    const float* bff    = (const float*)d_in[16];

    const size_t nTok = (size_t)B_ * L_ * H_;    // 1,572,864
    const size_t nPe  = (size_t)RRM * H_;        // 393,216
    unsigned short* p  = (unsigned short*)d_ws;
    unsigned short* qu  = p; p += nTok;
    unsigned short* qv  = p; p += nTok;
    unsigned short* kb  = p; p += nTok;
    unsigned short* vT  = p; p += nTok;
    unsigned short* rp  = p; p += nPe + 512;     // +1 pad row (corner n=415 read)
    unsigned short* Obf = p; p += nTok;

    // projections (cvt folded into staging), u/v biases + 1/8 scale folded into q
    gemm_nt<false><<<dim3(8, 48, 4), 256, 0, stream>>>(
        /*A0f..A3f*/ query, key, value, pe,
        /*Abf*/ nullptr,
        /*W0..W4*/ Wq, Wk, Wv, Wr, nullptr,
        /*b0..b4*/ bq, bk, bv, br, nullptr,
        /*ub,vbias*/ u_bias, v_bias,
        /*qu,qv,kb,vT,rp*/ qu, qv, kb, vT, rp,
        /*ff*/ nullptr);

    // fused Bt + scores + softmax + PV
    attn_fused<<<dim3(L_ / 32, B_ * NH_), 256, 0, stream>>>(
        qu, qv, kb, vT, rp, seqlen, Obf);

    // output projection (A bf16, W fp32 cvt-staged)
    gemm_nt<true><<<dim3(8, 48, 1), 256, 0, stream>>>(
        /*A0f..A3f*/ nullptr, nullptr, nullptr, nullptr,
        /*Abf*/ Obf,
        /*W0..W4*/ nullptr, nullptr, nullptr, nullptr, Wff,
        /*b0..b4*/ nullptr, nullptr, nullptr, nullptr, bff,
        /*ub,vbias*/ nullptr, nullptr,
        /*qu,qv,kb,vT,rp*/ nullptr, nullptr, nullptr, nullptr, nullptr,
        /*ff*/ (float*)d_out);
}

// Round 9
// 160.967 us; speedup vs baseline: 11.1701x; 1.0034x over previous
//
#include <hip/hip_runtime.h>
#include <hip/hip_bf16.h>

#define B_  8
#define L_  384
#define H_  512
#define NH_ 8
#define DH_ 64
#define RRM 768            // rproj rows computed; band uses [1,767]; +1 pad row

typedef short bf16x8 __attribute__((ext_vector_type(8)));
typedef float f32x4  __attribute__((ext_vector_type(4)));
#define MFMA_BF16 __builtin_amdgcn_mfma_f32_16x16x32_bf16

static __device__ __forceinline__ unsigned short f2bf(float f) {
    unsigned u = __builtin_bit_cast(unsigned, f);
    u += 0x7fffu + ((u >> 16) & 1u);           // RNE
    return (unsigned short)(u >> 16);
}
static __device__ __forceinline__ float bf2f(unsigned short s) {
    unsigned u = ((unsigned)s) << 16;
    return __builtin_bit_cast(float, u);
}

// async 16 B/lane global->LDS DMA (gfx950). LDS dest = wave-uniform base +
// lane*16; caller guarantees the base is wave-uniform (readfirstlane'd).
typedef unsigned int u32;
static __device__ __forceinline__ void glds16(const void* g, void* l) {
    __builtin_amdgcn_global_load_lds(
        (const __attribute__((address_space(1))) u32*)g,
        (__attribute__((address_space(3))) u32*)l, 16, 0, 0);
}

// ---------------------------------------------------------------------------
// fp32 -> bf16 bulk convert. chunk = 1024 elems (256 thr x 4); all regions
// are multiples of 1024 (no tails).
// ---------------------------------------------------------------------------
struct CvtArgs {
    const float* src[9];
    unsigned short* dst[9];
    int nchunks[9];
};
__global__ __launch_bounds__(256) void cvt_kernel(CvtArgs a) {
    int chunk = blockIdx.x;
    int r = 0;
    while (r < 8 && chunk >= a.nchunks[r]) { chunk -= a.nchunks[r]; r++; }
    const float4 v = ((const float4*)a.src[r])[chunk * 256 + threadIdx.x];
    ushort4 o;
    o.x = f2bf(v.x); o.y = f2bf(v.y); o.z = f2bf(v.z); o.w = f2bf(v.w);
    ((ushort4*)a.dst[r])[chunk * 256 + threadIdx.x] = o;
}

// ---------------------------------------------------------------------------
// bf16 MFMA NT GEMM, K=512, tile 64x64, BK=64, 4 waves (2x2 of 32x32).
// Staging: global_load_lds width=16, double-buffered, 1 barrier/iter.
// LDS layout: row-major 64x64, k8-slot XOR-swizzled by (row&7) -> ds_read_b128
// spreads over all 32 banks (conflict-free for b128).
// IS_FF=false: grid (8,48,4), z selects {q,k,v,pe} epilogues.
// IS_FF=true : grid (8,48,1), A=Obf, out = fp32 d_out + bias.
// ---------------------------------------------------------------------------
template <bool IS_FF>
__global__ __launch_bounds__(256) void gemm_nt(
    const unsigned short* __restrict__ A0, const unsigned short* __restrict__ A1,
    const unsigned short* __restrict__ A2, const unsigned short* __restrict__ A3,
    const unsigned short* __restrict__ A4,
    const unsigned short* __restrict__ W0, const unsigned short* __restrict__ W1,
    const unsigned short* __restrict__ W2, const unsigned short* __restrict__ W3,
    const unsigned short* __restrict__ W4,
    const float* __restrict__ b0, const float* __restrict__ b1,
    const float* __restrict__ b2, const float* __restrict__ b3,
    const float* __restrict__ b4,
    const float* __restrict__ ub, const float* __restrict__ vbias,
    unsigned short* __restrict__ qu, unsigned short* __restrict__ qv,
    unsigned short* __restrict__ kb, unsigned short* __restrict__ vT,
    unsigned short* __restrict__ rp, float* __restrict__ ff) {

    const int z = IS_FF ? 4 : blockIdx.z;
    if (!IS_FF && z == 3 && blockIdx.y >= 12) return;   // pe: 768 rows only
    const unsigned short* A = z == 0 ? A0 : z == 1 ? A1 : z == 2 ? A2 : z == 3 ? A3 : A4;
    const unsigned short* W = z == 0 ? W0 : z == 1 ? W1 : z == 2 ? W2 : z == 3 ? W3 : W4;
    const float* bias       = z == 0 ? b0 : z == 1 ? b1 : z == 2 ? b2 : z == 3 ? b3 : b4;

    __shared__ unsigned short AsF[2 * 64 * 64];   // [buf][row][slot*8], 16 KB
    __shared__ unsigned short BsF[2 * 64 * 64];

    const int tid = threadIdx.x;
    const int w = tid >> 6, lane = tid & 63;
    const int quad = lane >> 4, lm = lane & 15;
    const int wr = (w & 1) * 32, wc = (w >> 1) * 32;

    // staging: lane covers (row sr in an 8-row group, k8 slot sj); LDS slot sj
    // receives global k8 = sj ^ sr  (row&7 == sr for our bases).
    const int sr = lane >> 3, sj = lane & 7;
    const unsigned short* ga = A + (size_t)(blockIdx.y * 64 + w * 16 + sr) * 512 + (sj ^ sr) * 8;
    const unsigned short* gb = W + (size_t)(blockIdx.x * 64 + w * 16 + sr) * 512 + (sj ^ sr) * 8;

    // stage K-chunk kc into buffer buf: per wave 2 rows-groups x 2 operands
    auto stage = [&](int kc, int buf) {
        #pragma unroll
        for (int t = 0; t < 2; ++t) {
            int off = buf * 4096 + (w * 16 + t * 8) * 64;     // ushort index
            off = __builtin_amdgcn_readfirstlane(off);
            glds16(ga + kc * 64 + t * 8 * 512, &AsF[off]);
            glds16(gb + kc * 64 + t * 8 * 512, &BsF[off]);
        }
    };

    f32x4 acc[2][2] = {};
    stage(0, 0);
    for (int kc = 0; kc < 8; ++kc) {
        __syncthreads();                       // drains vmcnt for buf kc&1
        const int buf = kc & 1;
        if (kc < 7) stage(kc + 1, buf ^ 1);    // fly during compute
        const int base = buf * 4096;
        #pragma unroll
        for (int ks = 0; ks < 2; ++ks) {
            const int s = (((ks * 4 + quad) ^ (lm & 7))) * 8;  // swizzled slot
            bf16x8 a0 = *(const bf16x8*)&AsF[base + (wr + lm) * 64 + s];
            bf16x8 a1 = *(const bf16x8*)&AsF[base + (wr + 16 + lm) * 64 + s];
            bf16x8 w0 = *(const bf16x8*)&BsF[base + (wc + lm) * 64 + s];
            bf16x8 w1 = *(const bf16x8*)&BsF[base + (wc + 16 + lm) * 64 + s];
            acc[0][0] = MFMA_BF16(a0, w0, acc[0][0], 0, 0, 0);
            acc[0][1] = MFMA_BF16(a0, w1, acc[0][1], 0, 0, 0);
            acc[1][0] = MFMA_BF16(a1, w0, acc[1][0], 0, 0, 0);
            acc[1][1] = MFMA_BF16(a1, w1, acc[1][1], 0, 0, 0);
        }
    }

    #pragma unroll
    for (int si = 0; si < 2; ++si) {
        #pragma unroll
        for (int sj2 = 0; sj2 < 2; ++sj2) {
            #pragma unroll
            for (int reg = 0; reg < 4; ++reg) {
                const int r = blockIdx.y * 64 + wr + si * 16 + quad * 4 + reg;
                const int c = blockIdx.x * 64 + wc + sj2 * 16 + lm;
                const float val = acc[si][sj2][reg] + bias[c];
                if (IS_FF) {
                    ff[r * 512 + c] = val;
                } else if (z == 0) {
                    const int bb = r / L_, ii = r - bb * L_;
                    const int h = c >> 6, d = c & 63;
                    const int idx = ((bb * NH_ + h) * L_ + ii) * DH_ + d;
                    qu[idx] = f2bf((val + ub[c]) * 0.125f);     // pow2 scale: exact
                    qv[idx] = f2bf((val + vbias[c]) * 0.125f);
                } else if (z == 1) {
                    const int bb = r / L_, ii = r - bb * L_;
                    const int h = c >> 6, d = c & 63;
                    kb[((bb * NH_ + h) * L_ + ii) * DH_ + d] = f2bf(val);
                } else if (z == 2) {
                    const int bb = r / L_, ii = r - bb * L_;
                    const int h = c >> 6, d = c & 63;
                    vT[((bb * NH_ + h) * DH_ + d) * L_ + ii] = f2bf(val);
                } else {
                    rp[r * 512 + c] = f2bf(val);
                }
            }
        }
    }
}

// ---------------------------------------------------------------------------
// Fully fused attention per (bh, 32-row i-tile)  [unchanged from round 8]
// ---------------------------------------------------------------------------
#define BTSTR 424
__global__ __launch_bounds__(256) void attn_fused(
    const unsigned short* __restrict__ qu, const unsigned short* __restrict__ qv,
    const unsigned short* __restrict__ kbf, const unsigned short* __restrict__ vT,
    const unsigned short* __restrict__ rp, const int* __restrict__ seq_len,
    unsigned short* __restrict__ Obf) {
    __shared__ __align__(16) unsigned short BtP[32 * BTSTR];
    __shared__ float mx_red[32][2];
    __shared__ float sm_red[32][2];
    const int lane = threadIdx.x & 63, wv = threadIdx.x >> 6;
    const int quad = lane >> 4, lm = lane & 15;
    const int bh = blockIdx.y, b = bh >> 3, h = bh & 7;
    const int i0 = blockIdx.x * 32;
    const int sl = seq_len[b];
    const int msub = wv & 1, nh = wv >> 1;
    const int m_lo = 353 - i0;
    const int i_fr = i0 + msub * 16 + lm;

    {
        const unsigned short* qvr = qv + (size_t)(bh * L_ + i_fr) * DH_;
        const bf16x8 av0 = *(const bf16x8*)(qvr + quad * 8);
        const bf16x8 av1 = *(const bf16x8*)(qvr + 32 + quad * 8);
        #pragma unroll
        for (int ns = 0; ns < 13; ++ns) {
            const int ntl = nh * 208 + ns * 16;
            if (ntl <= sl + 30) {
                const int n = ntl + lm;
                const unsigned short* rrow = rp + (size_t)(m_lo + n) * 512 + h * 64;
                f32x4 bacc = {};
                bacc = MFMA_BF16(av0, *(const bf16x8*)(rrow + quad * 8), bacc, 0, 0, 0);
                bacc = MFMA_BF16(av1, *(const bf16x8*)(rrow + 32 + quad * 8), bacc, 0, 0, 0);
                #pragma unroll
                for (int reg = 0; reg < 4; ++reg) {
                    const int il = msub * 16 + quad * 4 + reg;
                    BtP[il * BTSTR + n] = f2bf(bacc[reg]);
                }
            }
        }
    }
    const unsigned short* qur = qu + (size_t)(bh * L_ + i_fr) * DH_;
    const bf16x8 au0 = *(const bf16x8*)(qur + quad * 8);
    const bf16x8 au1 = *(const bf16x8*)(qur + 32 + quad * 8);
    __syncthreads();

    f32x4 sc[12];
    #pragma unroll
    for (int ns = 0; ns < 12; ++ns) {
        const int jt = nh * 192 + ns * 16;
        if (jt < sl) {
            const unsigned short* krow = kbf + (size_t)(bh * L_ + jt + lm) * DH_;
            f32x4 a = {};
            a = MFMA_BF16(au0, *(const bf16x8*)(krow + quad * 8), a, 0, 0, 0);
            a = MFMA_BF16(au1, *(const bf16x8*)(krow + 32 + quad * 8), a, 0, 0, 0);
            sc[ns] = a;
        } else {
            sc[ns] = f32x4{-1e30f, -1e30f, -1e30f, -1e30f};
        }
    }
    const int jbase = nh * 192 + lm;
    #pragma unroll
    for (int ns = 0; ns < 12; ++ns) {
        const int j = jbase + ns * 16;
        #pragma unroll
        for (int reg = 0; reg < 4; ++reg) {
            const int il = msub * 16 + quad * 4 + reg;
            float val = -1e30f;
            if (j < sl) val = sc[ns][reg] + bf2f(BtP[il * BTSTR + (j - il + 31)]);
            sc[ns][reg] = val;
        }
    }

    const int il0 = msub * 16 + quad * 4;
    float mx4[4], sm4[4], inv4[4];
    #pragma unroll
    for (int reg = 0; reg < 4; ++reg) {
        float m = sc[0][reg];
        #pragma unroll
        for (int ns = 1; ns < 12; ++ns) m = fmaxf(m, sc[ns][reg]);
        #pragma unroll
        for (int o = 1; o < 16; o <<= 1) m = fmaxf(m, __shfl_xor(m, o));
        mx4[reg] = m;
    }
    if (lm == 0) {
        #pragma unroll
        for (int reg = 0; reg < 4; ++reg) mx_red[il0 + reg][nh] = mx4[reg];
    }
    __syncthreads();
    #pragma unroll
    for (int reg = 0; reg < 4; ++reg)
        mx4[reg] = fmaxf(mx_red[il0 + reg][0], mx_red[il0 + reg][1]);
    #pragma unroll
    for (int reg = 0; reg < 4; ++reg) sm4[reg] = 0.f;
    #pragma unroll
    for (int ns = 0; ns < 12; ++ns) {
        #pragma unroll
        for (int reg = 0; reg < 4; ++reg) {
            const float e = __expf(sc[ns][reg] - mx4[reg]);
            sc[ns][reg] = e;
            sm4[reg] += e;
        }
    }
    #pragma unroll
    for (int reg = 0; reg < 4; ++reg) {
        float s = sm4[reg];
        #pragma unroll
        for (int o = 1; o < 16; o <<= 1) s += __shfl_xor(s, o);
        sm4[reg] = s;
    }
    if (lm == 0) {
        #pragma unroll
        for (int reg = 0; reg < 4; ++reg) sm_red[il0 + reg][nh] = sm4[reg];
    }
    __syncthreads();
    #pragma unroll
    for (int reg = 0; reg < 4; ++reg)
        inv4[reg] = 1.f / (sm_red[il0 + reg][0] + sm_red[il0 + reg][1]);

    #pragma unroll
    for (int ns = 0; ns < 12; ++ns) {
        const int j = jbase + ns * 16;
        #pragma unroll
        for (int reg = 0; reg < 4; ++reg)
            BtP[(il0 + reg) * BTSTR + j] = f2bf(sc[ns][reg] * inv4[reg]);
    }
    __syncthreads();

    {
        const int pr = msub * 16 + lm;
        const int nkc = (sl + 31) >> 5;
        f32x4 oacc[2] = {};
        for (int kc = 0; kc < nkc; ++kc) {
            const bf16x8 af = *(const bf16x8*)&BtP[pr * BTSTR + kc * 32 + quad * 8];
            #pragma unroll
            for (int t = 0; t < 2; ++t) {
                const int n = nh * 32 + t * 16 + lm;
                const unsigned short* vrow = vT + (size_t)(bh * DH_ + n) * L_ + kc * 32 + quad * 8;
                oacc[t] = MFMA_BF16(af, *(const bf16x8*)(vrow), oacc[t], 0, 0, 0);
            }
        }
        #pragma unroll
        for (int t = 0; t < 2; ++t) {
            #pragma unroll
            for (int reg = 0; reg < 4; ++reg) {
                const int i = i0 + msub * 16 + quad * 4 + reg;
                const int d = nh * 32 + t * 16 + lm;
                Obf[(size_t)(b * L_ + i) * H_ + h * DH_ + d] = f2bf(oacc[t][reg]);
            }
        }
    }
}

extern "C" void kernel_launch(void* const* d_in, const int* in_sizes, int n_in,
                              void* d_out, int out_size, void* d_ws, size_t ws_size,
                              hipStream_t stream) {
    const float* key    = (const float*)d_in[0];
    const float* query  = (const float*)d_in[1];
    const float* value  = (const float*)d_in[2];
    const int*   seqlen = (const int*)d_in[3];
    const float* pe     = (const float*)d_in[4];
    const float* Wk     = (const float*)d_in[5];
    const float* bk     = (const float*)d_in[6];
    const float* Wq     = (const float*)d_in[7];
    const float* bq     = (const float*)d_in[8];
    const float* Wv     = (const float*)d_in[9];
    const float* bv     = (const float*)d_in[10];
    const float* Wr     = (const float*)d_in[11];
    const float* br     = (const float*)d_in[12];
    const float* u_bias = (const float*)d_in[13];
    const float* v_bias = (const float*)d_in[14];
    const float* Wff    = (const float*)d_in[15];
    const float* bff    = (const float*)d_in[16];

    const size_t nTok = (size_t)B_ * L_ * H_;    // 1,572,864
    const size_t nPe  = (size_t)RRM * H_;        // 393,216
    const size_t nW   = (size_t)H_ * H_;         // 262,144
    unsigned short* p  = (unsigned short*)d_ws;
    unsigned short* qbf  = p; p += nTok;         // aliased as Obf after proj
    unsigned short* kin  = p; p += nTok;
    unsigned short* vin  = p; p += nTok;
    unsigned short* pebf = p; p += nPe;
    unsigned short* Wqb  = p; p += nW;
    unsigned short* Wkb  = p; p += nW;
    unsigned short* Wvb  = p; p += nW;
    unsigned short* Wrb  = p; p += nW;
    unsigned short* Wffb = p; p += nW;
    unsigned short* qu   = p; p += nTok;
    unsigned short* qv   = p; p += nTok;
    unsigned short* kb   = p; p += nTok;
    unsigned short* vT   = p; p += nTok;
    unsigned short* rp   = p; p += nPe + 512;    // +1 pad row (corner n=415, never read back)
    unsigned short* Obf  = qbf;                  // disjoint lifetime

    CvtArgs ca;
    ca.src[0] = query;  ca.dst[0] = qbf;  ca.nchunks[0] = 1536;
    ca.src[1] = key;    ca.dst[1] = kin;  ca.nchunks[1] = 1536;
    ca.src[2] = value;  ca.dst[2] = vin;  ca.nchunks[2] = 1536;
    ca.src[3] = pe;     ca.dst[3] = pebf; ca.nchunks[3] = 384;   // first 768 rows
    ca.src[4] = Wq;     ca.dst[4] = Wqb;  ca.nchunks[4] = 256;
    ca.src[5] = Wk;     ca.dst[5] = Wkb;  ca.nchunks[5] = 256;
    ca.src[6] = Wv;     ca.dst[6] = Wvb;  ca.nchunks[6] = 256;
    ca.src[7] = Wr;     ca.dst[7] = Wrb;  ca.nchunks[7] = 256;
    ca.src[8] = Wff;    ca.dst[8] = Wffb; ca.nchunks[8] = 256;
    cvt_kernel<<<6272, 256, 0, stream>>>(ca);

    // projections: u/v biases + 1/8 scale folded into q epilogue
    gemm_nt<false><<<dim3(8, 48, 4), 256, 0, stream>>>(
        /*A0..A4*/ qbf, kin, vin, pebf, nullptr,
        /*W0..W4*/ Wqb, Wkb, Wvb, Wrb, nullptr,
        /*b0..b4*/ bq, bk, bv, br, nullptr,
        /*ub,vbias*/ u_bias, v_bias,
        /*qu,qv,kb,vT,rp*/ qu, qv, kb, vT, rp,
        /*ff*/ nullptr);

    // fused Bt + scores + softmax + PV
    attn_fused<<<dim3(L_ / 32, B_ * NH_), 256, 0, stream>>>(
        qu, qv, kb, vT, rp, seqlen, Obf);

    // output projection
    gemm_nt<true><<<dim3(8, 48, 1), 256, 0, stream>>>(
        /*A0..A4*/ nullptr, nullptr, nullptr, nullptr, Obf,
        /*W0..W4*/ nullptr, nullptr, nullptr, nullptr, Wffb,
        /*b0..b4*/ nullptr, nullptr, nullptr, nullptr, bff,
        /*ub,vbias*/ nullptr, nullptr,
        /*qu,qv,kb,vT,rp*/ nullptr, nullptr, nullptr, nullptr, nullptr,
        /*ff*/ (float*)d_out);
}